// Round 1
// baseline (5308.589 us; speedup 1.0000x reference)
//
#include <hip/hip_runtime.h>

#define NB 4096
#define SH 64
#define SD 32
#define HID 256

__device__ __forceinline__ float geluf(float x){
    return 0.5f * x * (1.0f + erff(x * 0.70710678118654752440f));
}
__device__ __forceinline__ unsigned short f2bf(float x){
    unsigned b = __float_as_uint(x);
    b += 0x7fffu + ((b >> 16) & 1u);
    return (unsigned short)(b >> 16);
}
__device__ __forceinline__ float bflo(unsigned u){ return __uint_as_float(u << 16); }
__device__ __forceinline__ float bfhi(unsigned u){ return __uint_as_float(u & 0xffff0000u); }

// scatter-form conv contribution: input position P feeds acc[P-k] with weight w[k]
#define CONTRIB(P, V) \
    { if ((P) <= 63)               acc[(P)]   += w0v*(V); \
      if ((P) >= 1 && (P) <= 64)   acc[(P)-1] += w1v*(V); \
      if ((P) >= 2 && (P) <= 65)   acc[(P)-2] += w2v*(V); \
      if ((P) >= 3 && (P) <= 66)   acc[(P)-3] += w3v*(V); \
      if ((P) >= 4)                acc[(P)-4] += w4v*(V); }

// ---------------- Kernel 1: fused conv0->conv1->conv2->meanpool ----------------
// one block per batch, 256 threads = 256 output channels
__global__ __launch_bounds__(256) void conv_kernel(
    const float* __restrict__ A,
    const float* __restrict__ W0, const float* __restrict__ B0,
    const float* __restrict__ W1, const float* __restrict__ B1,
    const float* __restrict__ W2, const float* __restrict__ B2,
    float* __restrict__ pooled)
{
    __shared__ float xs[32 * 69];            // input, halo t=-2..65 at idx 0..67, pad stride 69
    __shared__ unsigned short hs[256 * 70];  // bf16 hidden, halo'd, stride 70 (2-way banks = free)

    const int tid = threadIdx.x;
    const int b   = blockIdx.x;
    const int co  = tid;

    // stage action[b] (H,D) -> xs[ci][t+2]
    #pragma unroll
    for (int r = 0; r < 8; ++r){
        int e = tid + (r << 8);
        int t = e >> 5, ci = e & 31;
        xs[ci * 69 + t + 2] = A[(size_t)b * 2048 + e];
    }
    if (tid < 32){
        xs[tid*69+0]=0.f; xs[tid*69+1]=0.f; xs[tid*69+66]=0.f; xs[tid*69+67]=0.f; xs[tid*69+68]=0.f;
    }
    __syncthreads();

    float acc[64];

    // ---- conv0 (Cin=32, fp32 LDS) ----
    #pragma unroll
    for (int t = 0; t < 64; ++t) acc[t] = 0.f;
    {
        const float* Wp = W0 + co * (32 * 5);
        for (int ci = 0; ci < 32; ++ci){
            float w0v = Wp[ci*5+0], w1v = Wp[ci*5+1], w2v = Wp[ci*5+2],
                  w3v = Wp[ci*5+3], w4v = Wp[ci*5+4];
            const float* row = &xs[ci * 69];
            #pragma unroll
            for (int p = 0; p < 68; ++p){ float v = row[p]; CONTRIB(p, v); }
        }
    }
    {
        float bv = B0[co];
        unsigned short* hr = &hs[co * 70];
        hr[0]=0; hr[1]=0; hr[66]=0; hr[67]=0; hr[68]=0; hr[69]=0;
        #pragma unroll
        for (int t = 0; t < 64; ++t) hr[t+2] = f2bf(geluf(acc[t] + bv));
    }
    __syncthreads();

    // ---- conv1 (Cin=256, bf16 LDS) ----
    #pragma unroll
    for (int t = 0; t < 64; ++t) acc[t] = 0.f;
    {
        const float* Wp = W1 + co * (256 * 5);
        for (int ci = 0; ci < 256; ++ci){
            float w0v = Wp[ci*5+0], w1v = Wp[ci*5+1], w2v = Wp[ci*5+2],
                  w3v = Wp[ci*5+3], w4v = Wp[ci*5+4];
            const unsigned short* row = &hs[ci * 70];
            #pragma unroll
            for (int i2 = 0; i2 < 34; ++i2){
                unsigned u = *(const unsigned*)(row + 2*i2);
                float v0 = bflo(u), v1 = bfhi(u);
                CONTRIB(2*i2,   v0);
                CONTRIB(2*i2+1, v1);
            }
        }
    }
    __syncthreads();   // everyone done READING hs before overwrite
    {
        float bv = B1[co];
        unsigned short* hr = &hs[co * 70];
        hr[0]=0; hr[1]=0; hr[66]=0; hr[67]=0; hr[68]=0; hr[69]=0;
        #pragma unroll
        for (int t = 0; t < 64; ++t) hr[t+2] = f2bf(geluf(acc[t] + bv));
    }
    __syncthreads();

    // ---- conv2 (Cin=256, bf16 LDS) + mean pool ----
    #pragma unroll
    for (int t = 0; t < 64; ++t) acc[t] = 0.f;
    {
        const float* Wp = W2 + co * (256 * 5);
        for (int ci = 0; ci < 256; ++ci){
            float w0v = Wp[ci*5+0], w1v = Wp[ci*5+1], w2v = Wp[ci*5+2],
                  w3v = Wp[ci*5+3], w4v = Wp[ci*5+4];
            const unsigned short* row = &hs[ci * 70];
            #pragma unroll
            for (int i2 = 0; i2 < 34; ++i2){
                unsigned u = *(const unsigned*)(row + 2*i2);
                float v0 = bflo(u), v1 = bfhi(u);
                CONTRIB(2*i2,   v0);
                CONTRIB(2*i2+1, v1);
            }
        }
    }
    {
        float bv = B2[co];
        float s = 0.f;
        #pragma unroll
        for (int t = 0; t < 64; ++t) s += geluf(acc[t] + bv);
        pooled[(size_t)b * 256 + co] = s * (1.0f / 64.0f);
    }
}

// ---------------- Kernel 2: heads + sort + interp + residual + losses ----------------
// 8 batches per block, 256 threads
__global__ __launch_bounds__(256) void heads_kernel(
    const float* __restrict__ A,
    const float* __restrict__ pooled,
    const float* __restrict__ proj_w, const float* __restrict__ proj_b,
    const float* __restrict__ val_w1, const float* __restrict__ val_b1,
    const float* __restrict__ val_w2, const float* __restrict__ val_b2,
    const float* __restrict__ pos_w1, const float* __restrict__ pos_b1,
    const float* __restrict__ pos_w2, const float* __restrict__ pos_b2,
    const float* __restrict__ res_w1, const float* __restrict__ res_b1,
    const float* __restrict__ res_w2, const float* __restrict__ res_b2,
    const float* __restrict__ mix_w,  const float* __restrict__ mix_b,
    float* __restrict__ accums)
{
    __shared__ float pool_sh[8][256];
    __shared__ float enc_sh [8][256];
    __shared__ float vh_sh  [8][256];
    __shared__ float ph_sh  [8][256];
    __shared__ float rh_sh  [8][256];
    __shared__ float av_sh  [8][128];
    __shared__ float avs_sh [8][128];
    __shared__ float psort_sh[8][4];
    __shared__ int   rank_sh [8][4];
    __shared__ float q_sh   [8][2];
    __shared__ float ml_sh  [8][2];
    __shared__ float spos_sh[8][4];
    __shared__ float wred[8], wred2[8];

    const int tid = threadIdx.x;
    const int b0  = blockIdx.x * 8;

    #pragma unroll
    for (int r = 0; r < 8; ++r)
        pool_sh[r][tid] = pooled[(size_t)b0 * 256 + (r << 8) + tid];
    __syncthreads();

    // stage A: enc = gelu(pooled @ proj_w + proj_b)
    {
        float acc[8];
        #pragma unroll
        for (int g = 0; g < 8; ++g) acc[g] = 0.f;
        for (int i = 0; i < 256; ++i){
            float w = proj_w[i * 256 + tid];
            #pragma unroll
            for (int g = 0; g < 8; ++g) acc[g] += pool_sh[g][i] * w;
        }
        float bb = proj_b[tid];
        #pragma unroll
        for (int g = 0; g < 8; ++g) enc_sh[g][tid] = geluf(acc[g] + bb);
    }
    __syncthreads();

    // stage B: three hidden heads from enc (fused over one i-loop)
    {
        float av_[8], ap_[8], ar_[8];
        #pragma unroll
        for (int g = 0; g < 8; ++g){ av_[g]=0.f; ap_[g]=0.f; ar_[g]=0.f; }
        for (int i = 0; i < 256; ++i){
            float wv = val_w1[i*256+tid], wp = pos_w1[i*256+tid], wr = res_w1[i*256+tid];
            #pragma unroll
            for (int g = 0; g < 8; ++g){
                float ev = enc_sh[g][i];
                av_[g] += ev*wv; ap_[g] += ev*wp; ar_[g] += ev*wr;
            }
        }
        float bv = val_b1[tid], bp = pos_b1[tid], br = res_b1[tid];
        #pragma unroll
        for (int g = 0; g < 8; ++g){
            vh_sh[g][tid] = geluf(av_[g] + bv);
            ph_sh[g][tid] = geluf(ap_[g] + bp);
            rh_sh[g][tid] = geluf(ar_[g] + br);
        }
    }
    __syncthreads();

    // stage C: anchor vals (1024 outs), raw positions, mix logits
    {
        float acc[4];
        #pragma unroll
        for (int u = 0; u < 4; ++u) acc[u] = 0.f;
        int j = tid & 127, gh = tid >> 7;
        for (int i = 0; i < 256; ++i){
            float w = val_w2[i * 128 + j];
            #pragma unroll
            for (int u = 0; u < 4; ++u) acc[u] += vh_sh[gh + 2*u][i] * w;
        }
        float bb = val_b2[j];
        #pragma unroll
        for (int u = 0; u < 4; ++u) av_sh[gh + 2*u][j] = acc[u] + bb;
    }
    if (tid < 32){
        int g = tid >> 2, k = tid & 3;
        float a = 0.f;
        for (int i = 0; i < 256; ++i) a += ph_sh[g][i] * pos_w2[i*4 + k];
        a += pos_b2[k];
        spos_sh[g][k] = 63.0f / (1.0f + expf(-a));   // sigmoid * (H-1)
    }
    if (tid < 16){
        int g = tid >> 1, c = tid & 1;
        float a = 0.f;
        for (int i = 0; i < 256; ++i) a += enc_sh[g][i] * mix_w[i*2 + c];
        ml_sh[g][c] = a + mix_b[c];
    }
    __syncthreads();

    // stage D0: per-batch stable sort (K=4), spacing, softmax, entropy atomics
    if (tid < 8){
        int g = tid;
        float sv[4] = { spos_sh[g][0], spos_sh[g][1], spos_sh[g][2], spos_sh[g][3] };
        #pragma unroll
        for (int i = 0; i < 4; ++i){
            int r = 0;
            #pragma unroll
            for (int jj = 0; jj < 4; ++jj){
                r += (sv[jj] < sv[i]) ? 1 : 0;
                if (jj < i) r += (sv[jj] == sv[i]) ? 1 : 0;   // stable ties
            }
            rank_sh[g][i] = r;
            psort_sh[g][r] = sv[i];
        }
        psort_sh[g][0] = 0.0f; psort_sh[g][3] = 63.0f;
        float p1 = psort_sh[g][1], p2 = psort_sh[g][2];
        float g1 = p1 - 0.0f, g2 = p2 - p1, g3 = 63.0f - p2;
        const float MG = 10.5f;  // 0.5*63/3
        float r1 = fmaxf(MG-g1, 0.f), r2 = fmaxf(MG-g2, 0.f), r3 = fmaxf(MG-g3, 0.f);
        float sp = (r1*r1 + r2*r2 + r3*r3) * (1.0f/3.0f);
        float l0 = ml_sh[g][0], l1 = ml_sh[g][1];
        float m = fmaxf(l0, l1);
        float e0 = expf(l0-m), e1 = expf(l1-m);
        float inv = 1.0f / (e0+e1);
        float q0 = e0*inv, q1 = e1*inv;
        q_sh[g][0] = q0; q_sh[g][1] = q1;
        float entc = q0*logf(q0+1e-8f) + q1*logf(q1+1e-8f);
        atomicAdd(&accums[2], entc);
        atomicAdd(&accums[3], q0);
        atomicAdd(&accums[4], q1);
        atomicAdd(&accums[5], sp);
    }
    __syncthreads();

    // scatter anchor vals into sorted order
    #pragma unroll
    for (int u = 0; u < 4; ++u){
        int g = (tid >> 7) + 2*u;
        int j = tid & 127;
        int r0 = j >> 5, d = j & 31;
        avs_sh[g][rank_sh[g][r0]*32 + d] = av_sh[g][j];
    }
    __syncthreads();

    // stage D: residual matmul + piecewise-linear interp + recon/L1
    float lsq = 0.f, ll1 = 0.f;
    for (int u = 0; u < 8; ++u){
        int e = tid + (u << 8);
        int t = e >> 5, d = e & 31;
        float tf = (float)t;
        float racc[8];
        #pragma unroll
        for (int g = 0; g < 8; ++g) racc[g] = 0.f;
        for (int i = 0; i < 256; ++i){
            float w = res_w2[i * 2048 + e];
            #pragma unroll
            for (int g = 0; g < 8; ++g) racc[g] += rh_sh[g][i] * w;
        }
        float rb = res_b2[e];
        #pragma unroll
        for (int g = 0; g < 8; ++g){
            float res = racc[g] + rb;
            float p1 = psort_sh[g][1], p2 = psort_sh[g][2];
            int cnt = (p1 <= tf) + (p2 <= tf) + (63.0f <= tf);
            int idx = cnt < 2 ? cnt : 2;
            float left = psort_sh[g][idx], right = psort_sh[g][idx+1];
            float w = (tf - left) / (right - left + 1e-8f);
            w = fminf(fmaxf(w, 0.f), 1.f);
            float vl = avs_sh[g][idx*32 + d], vr = avs_sh[g][idx*32 + 32 + d];
            float coarse = vl + w * (vr - vl);
            float a = A[(size_t)(b0+g) * 2048 + e];
            float fine = coarse + res;
            float recon = q_sh[g][0]*coarse + q_sh[g][1]*fine;
            float dd = recon - a;
            lsq += dd*dd;
            ll1 += fabsf(res);
        }
    }
    #pragma unroll
    for (int off = 32; off > 0; off >>= 1){
        lsq += __shfl_down(lsq, off);
        ll1 += __shfl_down(ll1, off);
    }
    int wid = tid >> 6;
    if ((tid & 63) == 0){ wred[wid] = lsq; wred2[wid] = ll1; }
    __syncthreads();
    if (tid == 0){
        atomicAdd(&accums[0], wred[0]+wred[1]+wred[2]+wred[3]);
        atomicAdd(&accums[1], wred2[0]+wred2[1]+wred2[2]+wred2[3]);
    }
}

// ---------------- Kernel 3: finalize ----------------
__global__ void finalize_kernel(const float* __restrict__ accums, float* __restrict__ out){
    float rs = accums[0], l1s = accums[1], ents = accums[2];
    float q0s = accums[3], q1s = accums[4], sps = accums[5];
    const float invN = 1.0f / (4096.0f * 2048.0f);
    const float invB = 1.0f / 4096.0f;
    float recon_loss = rs * invN;
    float l1   = l1s * invN;
    float ent  = -ents * invB;
    float mq0  = q0s * invB - 0.5f, mq1 = q1s * invB - 0.5f;
    float balance = mq0*mq0 + mq1*mq1;
    float spacing = sps * invB;
    out[0] = recon_loss + 0.05f*l1 + 0.01f*ent + 0.1f*balance + 0.1f*spacing;
}

extern "C" void kernel_launch(void* const* d_in, const int* in_sizes, int n_in,
                              void* d_out, int out_size, void* d_ws, size_t ws_size,
                              hipStream_t stream)
{
    const float* A      = (const float*)d_in[0];
    const float* W0     = (const float*)d_in[1];
    const float* B0     = (const float*)d_in[2];
    const float* W1     = (const float*)d_in[3];
    const float* B1     = (const float*)d_in[4];
    const float* W2     = (const float*)d_in[5];
    const float* B2     = (const float*)d_in[6];
    const float* proj_w = (const float*)d_in[7];
    const float* proj_b = (const float*)d_in[8];
    const float* val_w1 = (const float*)d_in[9];
    const float* val_b1 = (const float*)d_in[10];
    const float* val_w2 = (const float*)d_in[11];
    const float* val_b2 = (const float*)d_in[12];
    const float* pos_w1 = (const float*)d_in[13];
    const float* pos_b1 = (const float*)d_in[14];
    const float* pos_w2 = (const float*)d_in[15];
    const float* pos_b2 = (const float*)d_in[16];
    const float* res_w1 = (const float*)d_in[17];
    const float* res_b1 = (const float*)d_in[18];
    const float* res_w2 = (const float*)d_in[19];
    const float* res_b2 = (const float*)d_in[20];
    const float* mix_w  = (const float*)d_in[21];
    const float* mix_b  = (const float*)d_in[22];

    float* accums = (float*)d_ws;          // 6 accumulators (64-float slot)
    float* pooled = (float*)d_ws + 64;     // B x 256

    hipMemsetAsync(accums, 0, 64 * sizeof(float), stream);

    hipLaunchKernelGGL(conv_kernel, dim3(NB), dim3(256), 0, stream,
                       A, W0, B0, W1, B1, W2, B2, pooled);

    hipLaunchKernelGGL(heads_kernel, dim3(NB/8), dim3(256), 0, stream,
                       A, pooled,
                       proj_w, proj_b, val_w1, val_b1, val_w2, val_b2,
                       pos_w1, pos_b1, pos_w2, pos_b2,
                       res_w1, res_b1, res_w2, res_b2, mix_w, mix_b,
                       accums);

    hipLaunchKernelGGL(finalize_kernel, dim3(1), dim3(1), 0, stream,
                       accums, (float*)d_out);
}

// Round 2
// 790.131 us; speedup vs baseline: 6.7186x; 6.7186x over previous
//
#include <hip/hip_runtime.h>

#define NB 4096

typedef __attribute__((ext_vector_type(8))) __bf16 bf16x8;
typedef __attribute__((ext_vector_type(4))) float  f32x4;

__device__ __forceinline__ float geluf(float x){
    return 0.5f * x * (1.0f + erff(x * 0.70710678118654752440f));
}
__device__ __forceinline__ unsigned short f2bf(float x){
    unsigned b = __float_as_uint(x);
    b += 0x7fffu + ((b >> 16) & 1u);
    return (unsigned short)(b >> 16);
}

// ---------------- Kernel 0: pack conv weights into MFMA B-fragment order ----------------
// layout: [kk][gnt(16)][lane(64)][j(8)] ; element = W[co][ci][kc]
//   co = gnt*16 + (lane&15), ci = s*32 + (lane>>4)*8 + j, kc = kk>>3 (layers 1,2) / kk (layer 0, s=0)
#define TOT0 40960     // 5*16*64*8
#define TOT1 327680    // 40*16*64*8
__global__ __launch_bounds__(256) void pack_weights(
    const float* __restrict__ W0, const float* __restrict__ W1, const float* __restrict__ W2,
    unsigned short* __restrict__ wp0, unsigned short* __restrict__ wp1, unsigned short* __restrict__ wp2)
{
    int idx = blockIdx.x * 256 + threadIdx.x;
    if (idx < TOT0){
        int j = idx & 7, lane = (idx >> 3) & 63, gnt = (idx >> 9) & 15, kk = idx >> 13;
        int co = gnt*16 + (lane & 15), ci = (lane >> 4)*8 + j;
        wp0[idx] = f2bf(W0[co*160 + ci*5 + kk]);
    } else if (idx < TOT0 + TOT1){
        int t = idx - TOT0;
        int j = t & 7, lane = (t >> 3) & 63, gnt = (t >> 9) & 15, kk = t >> 13;
        int kc = kk >> 3, s = kk & 7;
        int co = gnt*16 + (lane & 15), ci = s*32 + (lane >> 4)*8 + j;
        wp1[t] = f2bf(W1[co*1280 + ci*5 + kc]);
    } else if (idx < TOT0 + 2*TOT1){
        int t = idx - TOT0 - TOT1;
        int j = t & 7, lane = (t >> 3) & 63, gnt = (t >> 9) & 15, kk = t >> 13;
        int kc = kk >> 3, s = kk & 7;
        int co = gnt*16 + (lane & 15), ci = s*32 + (lane >> 4)*8 + j;
        wp2[t] = f2bf(W2[co*1280 + ci*5 + kc]);
    }
}

// ---------------- Kernel 1: MFMA conv0->conv1->conv2->meanpool ----------------
// one block per batch, 4 waves; wave w owns cols [64w, 64w+64), all 64 rows (t)
#define HT_S 264   // ht row stride in elems (528 B = 132 dw == 4 mod 32 banks: 2-way free, 16B aligned)
#define XT_S 40    // xt row stride (80 B = 20 dw: 2-way free, 16B aligned)

__global__ __launch_bounds__(256, 3) void conv_mfma_kernel(
    const float* __restrict__ A,
    const float* __restrict__ B0, const float* __restrict__ B1, const float* __restrict__ B2,
    const unsigned short* __restrict__ wp0, const unsigned short* __restrict__ wp1,
    const unsigned short* __restrict__ wp2,
    float* __restrict__ pooled)
{
    __shared__ unsigned short xt[68 * XT_S];   // input bf16, rows = t+2 (halo 2), cols = ci(32)
    __shared__ unsigned short ht[68 * HT_S];   // hidden bf16, rows = t+2, cols = ci(256)

    const int tid  = threadIdx.x;
    const int b    = blockIdx.x;
    const int w    = tid >> 6;
    const int lane = tid & 63;
    const int l15  = lane & 15;
    const int q    = lane >> 4;
    const int w4   = w << 2;
    const int w64  = w << 6;
    const int q8   = q << 3;
    const int q4   = q << 2;
    const int lane8 = lane << 3;

    // zero halo rows (t=-2,-1,64,65 -> rows 0,1,66,67)
    for (int i = tid; i < 4 * HT_S; i += 256){
        int r = i / HT_S, c = i - r * HT_S;
        ht[(r < 2 ? r : r + 64) * HT_S + c] = 0;
    }
    if (tid < 160){
        int r = tid / XT_S, c = tid - r * XT_S;
        xt[(r < 2 ? r : r + 64) * XT_S + c] = 0;
    }
    // stage input (64 t x 32 ci fp32) -> xt bf16
    {
        const float* Ab = A + (size_t)b * 2048;
        int e0 = tid << 3;
        int t = e0 >> 5, c = e0 & 31;
        const float4* p = (const float4*)(Ab + e0);
        float4 v0 = p[0], v1 = p[1];
        union { unsigned short u[8]; bf16x8 v; } pk;
        pk.u[0]=f2bf(v0.x); pk.u[1]=f2bf(v0.y); pk.u[2]=f2bf(v0.z); pk.u[3]=f2bf(v0.w);
        pk.u[4]=f2bf(v1.x); pk.u[5]=f2bf(v1.y); pk.u[6]=f2bf(v1.z); pk.u[7]=f2bf(v1.w);
        *(bf16x8*)&xt[(t + 2) * XT_S + c] = pk.v;
    }
    __syncthreads();

    f32x4 acc[4][4];

    // ---- conv0: K = 32 per k-offset, 5 offsets ----
    #pragma unroll
    for (int mt = 0; mt < 4; ++mt)
        #pragma unroll
        for (int nt = 0; nt < 4; ++nt)
            acc[mt][nt] = (f32x4){0.f, 0.f, 0.f, 0.f};
    #pragma unroll
    for (int kc = 0; kc < 5; ++kc){
        bf16x8 Af[4], Bf[4];
        #pragma unroll
        for (int mt = 0; mt < 4; ++mt)
            Af[mt] = *(const bf16x8*)&xt[((mt << 4) + l15 + kc) * XT_S + q8];
        #pragma unroll
        for (int nt = 0; nt < 4; ++nt)
            Bf[nt] = *(const bf16x8*)(wp0 + (((kc << 4) + w4 + nt) << 9) + lane8);
        #pragma unroll
        for (int mt = 0; mt < 4; ++mt)
            #pragma unroll
            for (int nt = 0; nt < 4; ++nt)
                acc[mt][nt] = __builtin_amdgcn_mfma_f32_16x16x32_bf16(Af[mt], Bf[nt], acc[mt][nt], 0, 0, 0);
    }
    // epilogue conv0 -> ht
    {
        float bv[4];
        #pragma unroll
        for (int nt = 0; nt < 4; ++nt) bv[nt] = B0[w64 + (nt << 4) + l15];
        #pragma unroll
        for (int mt = 0; mt < 4; ++mt)
            #pragma unroll
            for (int nt = 0; nt < 4; ++nt)
                #pragma unroll
                for (int r = 0; r < 4; ++r){
                    float v = geluf(acc[mt][nt][r] + bv[nt]);
                    ht[((mt << 4) + q4 + r + 2) * HT_S + w64 + (nt << 4) + l15] = f2bf(v);
                }
    }
    __syncthreads();

#define LOADA(BUF, KK) \
    { _Pragma("unroll") \
      for (int mt = 0; mt < 4; ++mt) \
          BUF[mt] = *(const bf16x8*)&ht[((mt << 4) + l15 + ((KK) >> 3)) * HT_S + (((KK) & 7) << 5) + q8]; }
#define LOADB(BUF, KK, WP) \
    { _Pragma("unroll") \
      for (int nt = 0; nt < 4; ++nt) \
          BUF[nt] = *(const bf16x8*)((WP) + ((((KK) << 4) + w4 + nt) << 9) + lane8); }
#define DOMFMA(AB, BB) \
    { _Pragma("unroll") \
      for (int mt = 0; mt < 4; ++mt) \
          _Pragma("unroll") \
          for (int nt = 0; nt < 4; ++nt) \
              acc[mt][nt] = __builtin_amdgcn_mfma_f32_16x16x32_bf16(AB[mt], BB[nt], acc[mt][nt], 0, 0, 0); }

#define CONV_LAYER(WP) \
    { bf16x8 Af[4], Bf[4], Bn[4]; \
      LOADB(Bf, 0, WP); \
      for (int kk = 0; kk < 40; kk += 2){ \
          LOADA(Af, kk); \
          LOADB(Bn, kk + 1, WP); \
          DOMFMA(Af, Bf); \
          LOADA(Af, kk + 1); \
          if (kk + 2 < 40) LOADB(Bf, kk + 2, WP); \
          DOMFMA(Af, Bn); \
      } }

    // ---- conv1 ----
    #pragma unroll
    for (int mt = 0; mt < 4; ++mt)
        #pragma unroll
        for (int nt = 0; nt < 4; ++nt)
            acc[mt][nt] = (f32x4){0.f, 0.f, 0.f, 0.f};
    CONV_LAYER(wp1);
    __syncthreads();   // all ht reads done before overwrite
    {
        float bv[4];
        #pragma unroll
        for (int nt = 0; nt < 4; ++nt) bv[nt] = B1[w64 + (nt << 4) + l15];
        #pragma unroll
        for (int mt = 0; mt < 4; ++mt)
            #pragma unroll
            for (int nt = 0; nt < 4; ++nt)
                #pragma unroll
                for (int r = 0; r < 4; ++r){
                    float v = geluf(acc[mt][nt][r] + bv[nt]);
                    ht[((mt << 4) + q4 + r + 2) * HT_S + w64 + (nt << 4) + l15] = f2bf(v);
                }
    }
    __syncthreads();

    // ---- conv2 + mean pool ----
    #pragma unroll
    for (int mt = 0; mt < 4; ++mt)
        #pragma unroll
        for (int nt = 0; nt < 4; ++nt)
            acc[mt][nt] = (f32x4){0.f, 0.f, 0.f, 0.f};
    CONV_LAYER(wp2);
    {
        float bv[4];
        #pragma unroll
        for (int nt = 0; nt < 4; ++nt) bv[nt] = B2[w64 + (nt << 4) + l15];
        float s[4];
        #pragma unroll
        for (int nt = 0; nt < 4; ++nt){
            float acc_s = 0.f;
            #pragma unroll
            for (int mt = 0; mt < 4; ++mt)
                #pragma unroll
                for (int r = 0; r < 4; ++r)
                    acc_s += geluf(acc[mt][nt][r] + bv[nt]);
            s[nt] = acc_s;
        }
        #pragma unroll
        for (int nt = 0; nt < 4; ++nt){
            s[nt] += __shfl_xor(s[nt], 16);
            s[nt] += __shfl_xor(s[nt], 32);
        }
        if (q == 0){
            #pragma unroll
            for (int nt = 0; nt < 4; ++nt)
                pooled[(size_t)b * 256 + w64 + (nt << 4) + l15] = s[nt] * (1.0f / 64.0f);
        }
    }
}

// ---------------- Kernel 2: heads + sort + interp + residual + losses ----------------
__global__ __launch_bounds__(256) void heads_kernel(
    const float* __restrict__ A,
    const float* __restrict__ pooled,
    const float* __restrict__ proj_w, const float* __restrict__ proj_b,
    const float* __restrict__ val_w1, const float* __restrict__ val_b1,
    const float* __restrict__ val_w2, const float* __restrict__ val_b2,
    const float* __restrict__ pos_w1, const float* __restrict__ pos_b1,
    const float* __restrict__ pos_w2, const float* __restrict__ pos_b2,
    const float* __restrict__ res_w1, const float* __restrict__ res_b1,
    const float* __restrict__ res_w2, const float* __restrict__ res_b2,
    const float* __restrict__ mix_w,  const float* __restrict__ mix_b,
    float* __restrict__ accums)
{
    __shared__ float pool_sh[8][256];
    __shared__ float enc_sh [8][256];
    __shared__ float vh_sh  [8][256];
    __shared__ float ph_sh  [8][256];
    __shared__ float rh_sh  [8][256];
    __shared__ float av_sh  [8][128];
    __shared__ float avs_sh [8][128];
    __shared__ float psort_sh[8][4];
    __shared__ int   rank_sh [8][4];
    __shared__ float q_sh   [8][2];
    __shared__ float ml_sh  [8][2];
    __shared__ float spos_sh[8][4];
    __shared__ float wred[8], wred2[8];

    const int tid = threadIdx.x;
    const int b0  = blockIdx.x * 8;

    #pragma unroll
    for (int r = 0; r < 8; ++r)
        pool_sh[r][tid] = pooled[(size_t)b0 * 256 + (r << 8) + tid];
    __syncthreads();

    {
        float acc[8];
        #pragma unroll
        for (int g = 0; g < 8; ++g) acc[g] = 0.f;
        for (int i = 0; i < 256; ++i){
            float w = proj_w[i * 256 + tid];
            #pragma unroll
            for (int g = 0; g < 8; ++g) acc[g] += pool_sh[g][i] * w;
        }
        float bb = proj_b[tid];
        #pragma unroll
        for (int g = 0; g < 8; ++g) enc_sh[g][tid] = geluf(acc[g] + bb);
    }
    __syncthreads();

    {
        float av_[8], ap_[8], ar_[8];
        #pragma unroll
        for (int g = 0; g < 8; ++g){ av_[g]=0.f; ap_[g]=0.f; ar_[g]=0.f; }
        for (int i = 0; i < 256; ++i){
            float wv = val_w1[i*256+tid], wp = pos_w1[i*256+tid], wr = res_w1[i*256+tid];
            #pragma unroll
            for (int g = 0; g < 8; ++g){
                float ev = enc_sh[g][i];
                av_[g] += ev*wv; ap_[g] += ev*wp; ar_[g] += ev*wr;
            }
        }
        float bv = val_b1[tid], bp = pos_b1[tid], br = res_b1[tid];
        #pragma unroll
        for (int g = 0; g < 8; ++g){
            vh_sh[g][tid] = geluf(av_[g] + bv);
            ph_sh[g][tid] = geluf(ap_[g] + bp);
            rh_sh[g][tid] = geluf(ar_[g] + br);
        }
    }
    __syncthreads();

    {
        float acc[4];
        #pragma unroll
        for (int u = 0; u < 4; ++u) acc[u] = 0.f;
        int j = tid & 127, gh = tid >> 7;
        for (int i = 0; i < 256; ++i){
            float w = val_w2[i * 128 + j];
            #pragma unroll
            for (int u = 0; u < 4; ++u) acc[u] += vh_sh[gh + 2*u][i] * w;
        }
        float bb = val_b2[j];
        #pragma unroll
        for (int u = 0; u < 4; ++u) av_sh[gh + 2*u][j] = acc[u] + bb;
    }
    if (tid < 32){
        int g = tid >> 2, k = tid & 3;
        float a = 0.f;
        for (int i = 0; i < 256; ++i) a += ph_sh[g][i] * pos_w2[i*4 + k];
        a += pos_b2[k];
        spos_sh[g][k] = 63.0f / (1.0f + expf(-a));
    }
    if (tid < 16){
        int g = tid >> 1, c = tid & 1;
        float a = 0.f;
        for (int i = 0; i < 256; ++i) a += enc_sh[g][i] * mix_w[i*2 + c];
        ml_sh[g][c] = a + mix_b[c];
    }
    __syncthreads();

    if (tid < 8){
        int g = tid;
        float sv[4] = { spos_sh[g][0], spos_sh[g][1], spos_sh[g][2], spos_sh[g][3] };
        #pragma unroll
        for (int i = 0; i < 4; ++i){
            int r = 0;
            #pragma unroll
            for (int jj = 0; jj < 4; ++jj){
                r += (sv[jj] < sv[i]) ? 1 : 0;
                if (jj < i) r += (sv[jj] == sv[i]) ? 1 : 0;
            }
            rank_sh[g][i] = r;
            psort_sh[g][r] = sv[i];
        }
        psort_sh[g][0] = 0.0f; psort_sh[g][3] = 63.0f;
        float p1 = psort_sh[g][1], p2 = psort_sh[g][2];
        float g1 = p1 - 0.0f, g2 = p2 - p1, g3 = 63.0f - p2;
        const float MG = 10.5f;
        float r1 = fmaxf(MG-g1, 0.f), r2 = fmaxf(MG-g2, 0.f), r3 = fmaxf(MG-g3, 0.f);
        float sp = (r1*r1 + r2*r2 + r3*r3) * (1.0f/3.0f);
        float l0 = ml_sh[g][0], l1 = ml_sh[g][1];
        float m = fmaxf(l0, l1);
        float e0 = expf(l0-m), e1 = expf(l1-m);
        float inv = 1.0f / (e0+e1);
        float q0 = e0*inv, q1 = e1*inv;
        q_sh[g][0] = q0; q_sh[g][1] = q1;
        float entc = q0*logf(q0+1e-8f) + q1*logf(q1+1e-8f);
        atomicAdd(&accums[2], entc);
        atomicAdd(&accums[3], q0);
        atomicAdd(&accums[4], q1);
        atomicAdd(&accums[5], sp);
    }
    __syncthreads();

    #pragma unroll
    for (int u = 0; u < 4; ++u){
        int g = (tid >> 7) + 2*u;
        int j = tid & 127;
        int r0 = j >> 5, d = j & 31;
        avs_sh[g][rank_sh[g][r0]*32 + d] = av_sh[g][j];
    }
    __syncthreads();

    float lsq = 0.f, ll1 = 0.f;
    for (int u = 0; u < 8; ++u){
        int e = tid + (u << 8);
        int t = e >> 5, d = e & 31;
        float tf = (float)t;
        float racc[8];
        #pragma unroll
        for (int g = 0; g < 8; ++g) racc[g] = 0.f;
        for (int i = 0; i < 256; ++i){
            float w = res_w2[i * 2048 + e];
            #pragma unroll
            for (int g = 0; g < 8; ++g) racc[g] += rh_sh[g][i] * w;
        }
        float rb = res_b2[e];
        #pragma unroll
        for (int g = 0; g < 8; ++g){
            float res = racc[g] + rb;
            float p1 = psort_sh[g][1], p2 = psort_sh[g][2];
            int cnt = (p1 <= tf) + (p2 <= tf) + (63.0f <= tf);
            int idx = cnt < 2 ? cnt : 2;
            float left = psort_sh[g][idx], right = psort_sh[g][idx+1];
            float wgt = (tf - left) / (right - left + 1e-8f);
            wgt = fminf(fmaxf(wgt, 0.f), 1.f);
            float vl = avs_sh[g][idx*32 + d], vr = avs_sh[g][idx*32 + 32 + d];
            float coarse = vl + wgt * (vr - vl);
            float a = A[(size_t)(b0+g) * 2048 + e];
            float fine = coarse + res;
            float recon = q_sh[g][0]*coarse + q_sh[g][1]*fine;
            float dd = recon - a;
            lsq += dd*dd;
            ll1 += fabsf(res);
        }
    }
    #pragma unroll
    for (int off = 32; off > 0; off >>= 1){
        lsq += __shfl_down(lsq, off);
        ll1 += __shfl_down(ll1, off);
    }
    int wid = tid >> 6;
    if ((tid & 63) == 0){ wred[wid] = lsq; wred2[wid] = ll1; }
    __syncthreads();
    if (tid == 0){
        atomicAdd(&accums[0], wred[0]+wred[1]+wred[2]+wred[3]);
        atomicAdd(&accums[1], wred2[0]+wred2[1]+wred2[2]+wred2[3]);
    }
}

// ---------------- Kernel 3: finalize ----------------
__global__ void finalize_kernel(const float* __restrict__ accums, float* __restrict__ out){
    float rs = accums[0], l1s = accums[1], ents = accums[2];
    float q0s = accums[3], q1s = accums[4], sps = accums[5];
    const float invN = 1.0f / (4096.0f * 2048.0f);
    const float invB = 1.0f / 4096.0f;
    float recon_loss = rs * invN;
    float l1   = l1s * invN;
    float ent  = -ents * invB;
    float mq0  = q0s * invB - 0.5f, mq1 = q1s * invB - 0.5f;
    float balance = mq0*mq0 + mq1*mq1;
    float spacing = sps * invB;
    out[0] = recon_loss + 0.05f*l1 + 0.01f*ent + 0.1f*balance + 0.1f*spacing;
}

extern "C" void kernel_launch(void* const* d_in, const int* in_sizes, int n_in,
                              void* d_out, int out_size, void* d_ws, size_t ws_size,
                              hipStream_t stream)
{
    const float* A      = (const float*)d_in[0];
    const float* W0     = (const float*)d_in[1];
    const float* B0     = (const float*)d_in[2];
    const float* W1     = (const float*)d_in[3];
    const float* B1     = (const float*)d_in[4];
    const float* W2     = (const float*)d_in[5];
    const float* B2     = (const float*)d_in[6];
    const float* proj_w = (const float*)d_in[7];
    const float* proj_b = (const float*)d_in[8];
    const float* val_w1 = (const float*)d_in[9];
    const float* val_b1 = (const float*)d_in[10];
    const float* val_w2 = (const float*)d_in[11];
    const float* val_b2 = (const float*)d_in[12];
    const float* pos_w1 = (const float*)d_in[13];
    const float* pos_b1 = (const float*)d_in[14];
    const float* pos_w2 = (const float*)d_in[15];
    const float* pos_b2 = (const float*)d_in[16];
    const float* res_w1 = (const float*)d_in[17];
    const float* res_b1 = (const float*)d_in[18];
    const float* res_w2 = (const float*)d_in[19];
    const float* res_b2 = (const float*)d_in[20];
    const float* mix_w  = (const float*)d_in[21];
    const float* mix_b  = (const float*)d_in[22];

    float* accums = (float*)d_ws;                       // 64-float slot
    float* pooled = (float*)d_ws + 64;                  // 4096 x 256 f32
    unsigned short* wp0 = (unsigned short*)((char*)d_ws + (size_t)(64 + 4096*256) * 4);
    unsigned short* wp1 = wp0 + TOT0;
    unsigned short* wp2 = wp1 + TOT1;

    hipMemsetAsync(accums, 0, 64 * sizeof(float), stream);

    hipLaunchKernelGGL(pack_weights, dim3((TOT0 + 2*TOT1 + 255) / 256), dim3(256), 0, stream,
                       W0, W1, W2, wp0, wp1, wp2);

    hipLaunchKernelGGL(conv_mfma_kernel, dim3(NB), dim3(256), 0, stream,
                       A, B0, B1, B2, wp0, wp1, wp2, pooled);

    hipLaunchKernelGGL(heads_kernel, dim3(NB/8), dim3(256), 0, stream,
                       A, pooled,
                       proj_w, proj_b, val_w1, val_b1, val_w2, val_b2,
                       pos_w1, pos_b1, pos_w2, pos_b2,
                       res_w1, res_b1, res_w2, res_b2, mix_w, mix_b,
                       accums);

    hipLaunchKernelGGL(finalize_kernel, dim3(1), dim3(1), 0, stream,
                       accums, (float*)d_out);
}

// Round 3
// 600.842 us; speedup vs baseline: 8.8352x; 1.3150x over previous
//
#include <hip/hip_runtime.h>

#define NB 4096

typedef __attribute__((ext_vector_type(8))) __bf16 bf16x8;
typedef __attribute__((ext_vector_type(4))) float  f32x4;

// fast gelu: tanh form, hardware exp. max abs err ~1e-3 (<< bf16 rounding already present)
__device__ __forceinline__ float gelu_fast(float x){
    float x2 = x * x;
    float y  = x * (0.79788456f + 0.03567741f * x2);
    float e  = __expf(2.0f * y);
    float t  = 1.0f - 2.0f / (e + 1.0f);
    return 0.5f * x * (1.0f + t);
}
__device__ __forceinline__ unsigned short f2bf(float x){
    unsigned b = __float_as_uint(x);
    b += 0x7fffu + ((b >> 16) & 1u);
    return (unsigned short)(b >> 16);
}

// ---------------- pack offsets (elements) ----------------
#define O_WP0  0
#define O_WP1  40960
#define O_WP2  368640
#define O_PROJ 696320
#define O_VAL1 761856
#define O_POS1 827392
#define O_RES1 892928
#define O_VAL2 958464
#define O_RES2 991232
#define O_POS2 1515520
#define O_MIX  1519616
#define PK_TOTAL 1523712

__device__ __forceinline__ unsigned short pack_std_elem(const float* W, int N, int t){
    int j = t & 7, lane = (t >> 3) & 63, rest = t >> 9;
    int ntcnt = N >> 4;
    int nt = rest % ntcnt, kk = rest / ntcnt;
    int n = nt*16 + (lane & 15), k = kk*32 + ((lane >> 4) << 3) + j;
    return f2bf(W[k * N + n]);
}
__device__ __forceinline__ unsigned short pack_pad_elem(const float* W, int Nreal, int t){
    int j = t & 7, lane = (t >> 3) & 63, kk = t >> 9;
    int n = lane & 15, k = kk*32 + ((lane >> 4) << 3) + j;
    return (n < Nreal) ? f2bf(W[k * Nreal + n]) : (unsigned short)0;
}

__global__ __launch_bounds__(256) void pack_weights(
    const float* __restrict__ W0, const float* __restrict__ W1, const float* __restrict__ W2,
    const float* __restrict__ proj_w, const float* __restrict__ val_w1,
    const float* __restrict__ pos_w1, const float* __restrict__ res_w1,
    const float* __restrict__ val_w2, const float* __restrict__ res_w2,
    const float* __restrict__ pos_w2, const float* __restrict__ mix_w,
    unsigned short* __restrict__ pk)
{
    int idx = blockIdx.x * 256 + threadIdx.x;
    if (idx >= PK_TOTAL) return;
    if (idx < O_WP1){
        int t = idx;
        int j = t & 7, lane = (t >> 3) & 63, gnt = (t >> 9) & 15, kk = t >> 13;
        int co = gnt*16 + (lane & 15), ci = (lane >> 4)*8 + j;
        pk[idx] = f2bf(W0[co*160 + ci*5 + kk]);
    } else if (idx < O_WP2){
        int t = idx - O_WP1;
        int j = t & 7, lane = (t >> 3) & 63, gnt = (t >> 9) & 15, kk = t >> 13;
        int kc = kk >> 3, s = kk & 7;
        int co = gnt*16 + (lane & 15), ci = s*32 + (lane >> 4)*8 + j;
        pk[idx] = f2bf(W1[co*1280 + ci*5 + kc]);
    } else if (idx < O_PROJ){
        int t = idx - O_WP2;
        int j = t & 7, lane = (t >> 3) & 63, gnt = (t >> 9) & 15, kk = t >> 13;
        int kc = kk >> 3, s = kk & 7;
        int co = gnt*16 + (lane & 15), ci = s*32 + (lane >> 4)*8 + j;
        pk[idx] = f2bf(W2[co*1280 + ci*5 + kc]);
    }
    else if (idx < O_VAL1) pk[idx] = pack_std_elem(proj_w, 256, idx - O_PROJ);
    else if (idx < O_POS1) pk[idx] = pack_std_elem(val_w1, 256, idx - O_VAL1);
    else if (idx < O_RES1) pk[idx] = pack_std_elem(pos_w1, 256, idx - O_POS1);
    else if (idx < O_VAL2) pk[idx] = pack_std_elem(res_w1, 256, idx - O_RES1);
    else if (idx < O_RES2) pk[idx] = pack_std_elem(val_w2, 128, idx - O_VAL2);
    else if (idx < O_POS2) pk[idx] = pack_std_elem(res_w2, 2048, idx - O_RES2);
    else if (idx < O_MIX)  pk[idx] = pack_pad_elem(pos_w2, 4, idx - O_POS2);
    else                   pk[idx] = pack_pad_elem(mix_w, 2, idx - O_MIX);
}

// ---------------- Kernel 1: MFMA conv0->conv1->conv2->meanpool ----------------
#define HT_S 264
#define XT_S 40

__global__ __launch_bounds__(256, 3) void conv_mfma_kernel(
    const float* __restrict__ A,
    const float* __restrict__ B0, const float* __restrict__ B1, const float* __restrict__ B2,
    const unsigned short* __restrict__ wp0, const unsigned short* __restrict__ wp1,
    const unsigned short* __restrict__ wp2,
    float* __restrict__ pooled)
{
    __shared__ unsigned short xt[68 * XT_S];
    __shared__ unsigned short ht[68 * HT_S];

    const int tid  = threadIdx.x;
    const int b    = blockIdx.x;
    const int w    = tid >> 6;
    const int lane = tid & 63;
    const int l15  = lane & 15;
    const int q    = lane >> 4;
    const int w4   = w << 2;
    const int w64  = w << 6;
    const int q8   = q << 3;
    const int q4   = q << 2;
    const int lane8 = lane << 3;

    for (int i = tid; i < 4 * HT_S; i += 256){
        int r = i / HT_S, c = i - r * HT_S;
        ht[(r < 2 ? r : r + 64) * HT_S + c] = 0;
    }
    if (tid < 160){
        int r = tid / XT_S, c = tid - r * XT_S;
        xt[(r < 2 ? r : r + 64) * XT_S + c] = 0;
    }
    {
        const float* Ab = A + (size_t)b * 2048;
        int e0 = tid << 3;
        int t = e0 >> 5, c = e0 & 31;
        const float4* p = (const float4*)(Ab + e0);
        float4 v0 = p[0], v1 = p[1];
        union { unsigned short u[8]; bf16x8 v; } pkv;
        pkv.u[0]=f2bf(v0.x); pkv.u[1]=f2bf(v0.y); pkv.u[2]=f2bf(v0.z); pkv.u[3]=f2bf(v0.w);
        pkv.u[4]=f2bf(v1.x); pkv.u[5]=f2bf(v1.y); pkv.u[6]=f2bf(v1.z); pkv.u[7]=f2bf(v1.w);
        *(bf16x8*)&xt[(t + 2) * XT_S + c] = pkv.v;
    }
    __syncthreads();

    f32x4 acc[4][4];

    #pragma unroll
    for (int mt = 0; mt < 4; ++mt)
        #pragma unroll
        for (int nt = 0; nt < 4; ++nt)
            acc[mt][nt] = (f32x4){0.f, 0.f, 0.f, 0.f};
    #pragma unroll
    for (int kc = 0; kc < 5; ++kc){
        bf16x8 Af[4], Bf[4];
        #pragma unroll
        for (int mt = 0; mt < 4; ++mt)
            Af[mt] = *(const bf16x8*)&xt[((mt << 4) + l15 + kc) * XT_S + q8];
        #pragma unroll
        for (int nt = 0; nt < 4; ++nt)
            Bf[nt] = *(const bf16x8*)(wp0 + (((kc << 4) + w4 + nt) << 9) + lane8);
        #pragma unroll
        for (int mt = 0; mt < 4; ++mt)
            #pragma unroll
            for (int nt = 0; nt < 4; ++nt)
                acc[mt][nt] = __builtin_amdgcn_mfma_f32_16x16x32_bf16(Af[mt], Bf[nt], acc[mt][nt], 0, 0, 0);
    }
    {
        float bv[4];
        #pragma unroll
        for (int nt = 0; nt < 4; ++nt) bv[nt] = B0[w64 + (nt << 4) + l15];
        #pragma unroll
        for (int mt = 0; mt < 4; ++mt)
            #pragma unroll
            for (int nt = 0; nt < 4; ++nt)
                #pragma unroll
                for (int r = 0; r < 4; ++r){
                    float v = gelu_fast(acc[mt][nt][r] + bv[nt]);
                    ht[((mt << 4) + q4 + r + 2) * HT_S + w64 + (nt << 4) + l15] = f2bf(v);
                }
    }
    __syncthreads();

#define LOADA(BUF, KK) \
    { _Pragma("unroll") \
      for (int mt = 0; mt < 4; ++mt) \
          BUF[mt] = *(const bf16x8*)&ht[((mt << 4) + l15 + ((KK) >> 3)) * HT_S + (((KK) & 7) << 5) + q8]; }
#define LOADB(BUF, KK, WP) \
    { _Pragma("unroll") \
      for (int nt = 0; nt < 4; ++nt) \
          BUF[nt] = *(const bf16x8*)((WP) + ((((KK) << 4) + w4 + nt) << 9) + lane8); }
#define DOMFMA(AB, BB) \
    { _Pragma("unroll") \
      for (int mt = 0; mt < 4; ++mt) \
          _Pragma("unroll") \
          for (int nt = 0; nt < 4; ++nt) \
              acc[mt][nt] = __builtin_amdgcn_mfma_f32_16x16x32_bf16(AB[mt], BB[nt], acc[mt][nt], 0, 0, 0); }

#define CONV_LAYER(WP) \
    { bf16x8 Af[4], Bf[4], Bn[4]; \
      LOADB(Bf, 0, WP); \
      for (int kk = 0; kk < 40; kk += 2){ \
          LOADA(Af, kk); \
          LOADB(Bn, kk + 1, WP); \
          DOMFMA(Af, Bf); \
          LOADA(Af, kk + 1); \
          if (kk + 2 < 40) LOADB(Bf, kk + 2, WP); \
          DOMFMA(Af, Bn); \
      } }

    #pragma unroll
    for (int mt = 0; mt < 4; ++mt)
        #pragma unroll
        for (int nt = 0; nt < 4; ++nt)
            acc[mt][nt] = (f32x4){0.f, 0.f, 0.f, 0.f};
    CONV_LAYER(wp1);
    __syncthreads();
    {
        float bv[4];
        #pragma unroll
        for (int nt = 0; nt < 4; ++nt) bv[nt] = B1[w64 + (nt << 4) + l15];
        #pragma unroll
        for (int mt = 0; mt < 4; ++mt)
            #pragma unroll
            for (int nt = 0; nt < 4; ++nt)
                #pragma unroll
                for (int r = 0; r < 4; ++r){
                    float v = gelu_fast(acc[mt][nt][r] + bv[nt]);
                    ht[((mt << 4) + q4 + r + 2) * HT_S + w64 + (nt << 4) + l15] = f2bf(v);
                }
    }
    __syncthreads();

    #pragma unroll
    for (int mt = 0; mt < 4; ++mt)
        #pragma unroll
        for (int nt = 0; nt < 4; ++nt)
            acc[mt][nt] = (f32x4){0.f, 0.f, 0.f, 0.f};
    CONV_LAYER(wp2);
    {
        float bv[4];
        #pragma unroll
        for (int nt = 0; nt < 4; ++nt) bv[nt] = B2[w64 + (nt << 4) + l15];
        float s[4];
        #pragma unroll
        for (int nt = 0; nt < 4; ++nt){
            float acc_s = 0.f;
            #pragma unroll
            for (int mt = 0; mt < 4; ++mt)
                #pragma unroll
                for (int r = 0; r < 4; ++r)
                    acc_s += gelu_fast(acc[mt][nt][r] + bv[nt]);
            s[nt] = acc_s;
        }
        #pragma unroll
        for (int nt = 0; nt < 4; ++nt){
            s[nt] += __shfl_xor(s[nt], 16);
            s[nt] += __shfl_xor(s[nt], 32);
        }
        if (q == 0){
            #pragma unroll
            for (int nt = 0; nt < 4; ++nt)
                pooled[(size_t)b * 256 + w64 + (nt << 4) + l15] = s[nt] * (1.0f / 64.0f);
        }
    }
}

// ---------------- Kernel 2: heads, all-MFMA, 16 batches/block ----------------
#define AS 264

__global__ __launch_bounds__(256) void heads_mfma_kernel(
    const float* __restrict__ A, const float* __restrict__ pooled,
    const float* __restrict__ proj_b, const float* __restrict__ val_b1,
    const float* __restrict__ pos_b1, const float* __restrict__ res_b1,
    const float* __restrict__ val_b2, const float* __restrict__ pos_b2,
    const float* __restrict__ res_b2, const float* __restrict__ mix_b,
    const unsigned short* __restrict__ pk,
    float* __restrict__ accums)
{
    __shared__ unsigned short pb [16 * AS];
    __shared__ unsigned short eb [16 * AS];
    __shared__ unsigned short vb [16 * AS];
    __shared__ unsigned short phb[16 * AS];
    __shared__ unsigned short rhb[16 * AS];
    __shared__ float av [16 * 132];
    __shared__ float avs[16 * 132];
    __shared__ float psort[16][4];
    __shared__ int   rank [16][4];
    __shared__ float qsh  [16][2];
    __shared__ float mlsh [16][2];
    __shared__ float sposh[16][4];
    __shared__ float wred[4], wred2[4];

    const int tid  = threadIdx.x;
    const int b0   = blockIdx.x * 16;
    const int w    = tid >> 6;
    const int lane = tid & 63;
    const int l15  = lane & 15;
    const int q    = lane >> 4;
    const int q8   = q << 3;
    const int q4   = q << 2;

    // stage pooled -> pb (bf16, A-frag layout)
    {
        int g = tid >> 4, seg = tid & 15;
        const float* ps = pooled + ((size_t)(b0 + g) << 8) + (seg << 4);
        const float4* p4 = (const float4*)ps;
        float4 v0 = p4[0], v1 = p4[1], v2 = p4[2], v3 = p4[3];
        union { unsigned short u[8]; bf16x8 v; } k0, k1;
        k0.u[0]=f2bf(v0.x); k0.u[1]=f2bf(v0.y); k0.u[2]=f2bf(v0.z); k0.u[3]=f2bf(v0.w);
        k0.u[4]=f2bf(v1.x); k0.u[5]=f2bf(v1.y); k0.u[6]=f2bf(v1.z); k0.u[7]=f2bf(v1.w);
        k1.u[0]=f2bf(v2.x); k1.u[1]=f2bf(v2.y); k1.u[2]=f2bf(v2.z); k1.u[3]=f2bf(v2.w);
        k1.u[4]=f2bf(v3.x); k1.u[5]=f2bf(v3.y); k1.u[6]=f2bf(v3.z); k1.u[7]=f2bf(v3.w);
        *(bf16x8*)&pb[g * AS + (seg << 4)]     = k0.v;
        *(bf16x8*)&pb[g * AS + (seg << 4) + 8] = k1.v;
    }
    __syncthreads();

// M=16 x N=256 x K=256 GEMM; wave w covers n in [64w, 64w+64); gelu epilogue to DST (A-layout)
#define HGEMM256(ASRC, GOFF, BIAS, DST) \
    { f32x4 hacc[4]; \
      _Pragma("unroll") for (int nt = 0; nt < 4; ++nt) hacc[nt] = (f32x4){0.f,0.f,0.f,0.f}; \
      _Pragma("unroll") for (int kk = 0; kk < 8; ++kk){ \
          bf16x8 af = *(const bf16x8*)&(ASRC)[l15 * AS + (kk << 5) + q8]; \
          _Pragma("unroll") for (int nt = 0; nt < 4; ++nt){ \
              bf16x8 bfr = *(const bf16x8*)(pk + (GOFF) + (size_t)((((kk << 4) + (w << 2) + nt) << 6) + lane) * 8); \
              hacc[nt] = __builtin_amdgcn_mfma_f32_16x16x32_bf16(af, bfr, hacc[nt], 0, 0, 0); } } \
      _Pragma("unroll") for (int nt = 0; nt < 4; ++nt){ \
          int n = (w << 6) + (nt << 4) + l15; \
          float bv = (BIAS)[n]; \
          _Pragma("unroll") for (int r = 0; r < 4; ++r) \
              (DST)[(q4 + r) * AS + n] = f2bf(gelu_fast(hacc[nt][r] + bv)); } }

    // stage A: enc
    HGEMM256(pb, O_PROJ, proj_b, eb);
    __syncthreads();

    // stage B: three hidden heads
    HGEMM256(eb, O_VAL1, val_b1, vb);
    HGEMM256(eb, O_POS1, pos_b1, phb);
    HGEMM256(eb, O_RES1, res_b1, rhb);
    __syncthreads();

    // stage C: anchor vals (N=128), pos head (wave0), mix head (wave1)
    {
        f32x4 acc2[2];
        #pragma unroll
        for (int nt = 0; nt < 2; ++nt) acc2[nt] = (f32x4){0.f,0.f,0.f,0.f};
        #pragma unroll
        for (int kk = 0; kk < 8; ++kk){
            bf16x8 af = *(const bf16x8*)&vb[l15 * AS + (kk << 5) + q8];
            #pragma unroll
            for (int nt = 0; nt < 2; ++nt){
                bf16x8 bfr = *(const bf16x8*)(pk + O_VAL2 + (size_t)(((kk*8 + w*2 + nt) << 6) + lane) * 8);
                acc2[nt] = __builtin_amdgcn_mfma_f32_16x16x32_bf16(af, bfr, acc2[nt], 0, 0, 0);
            }
        }
        #pragma unroll
        for (int nt = 0; nt < 2; ++nt){
            int j = (w << 5) + (nt << 4) + l15;
            float bv = val_b2[j];
            #pragma unroll
            for (int r = 0; r < 4; ++r)
                av[(q4 + r) * 132 + j] = acc2[nt][r] + bv;
        }
    }
    if (w == 0){
        f32x4 accp = (f32x4){0.f,0.f,0.f,0.f};
        #pragma unroll
        for (int kk = 0; kk < 8; ++kk){
            bf16x8 af  = *(const bf16x8*)&phb[l15 * AS + (kk << 5) + q8];
            bf16x8 bfr = *(const bf16x8*)(pk + O_POS2 + (size_t)((kk << 6) + lane) * 8);
            accp = __builtin_amdgcn_mfma_f32_16x16x32_bf16(af, bfr, accp, 0, 0, 0);
        }
        if (l15 < 4){
            float bv = pos_b2[l15];
            #pragma unroll
            for (int r = 0; r < 4; ++r){
                float raw = accp[r] + bv;
                sposh[q4 + r][l15] = 63.0f / (1.0f + __expf(-raw));
            }
        }
    } else if (w == 1){
        f32x4 accm = (f32x4){0.f,0.f,0.f,0.f};
        #pragma unroll
        for (int kk = 0; kk < 8; ++kk){
            bf16x8 af  = *(const bf16x8*)&eb[l15 * AS + (kk << 5) + q8];
            bf16x8 bfr = *(const bf16x8*)(pk + O_MIX + (size_t)((kk << 6) + lane) * 8);
            accm = __builtin_amdgcn_mfma_f32_16x16x32_bf16(af, bfr, accm, 0, 0, 0);
        }
        if (l15 < 2){
            #pragma unroll
            for (int r = 0; r < 4; ++r)
                mlsh[q4 + r][l15] = accm[r] + mix_b[l15];
        }
    }
    __syncthreads();

    // sort + spacing + softmax + entropy
    if (tid < 16){
        int g = tid;
        float sv[4] = { sposh[g][0], sposh[g][1], sposh[g][2], sposh[g][3] };
        #pragma unroll
        for (int i = 0; i < 4; ++i){
            int r = 0;
            #pragma unroll
            for (int jj = 0; jj < 4; ++jj){
                r += (sv[jj] < sv[i]) ? 1 : 0;
                if (jj < i) r += (sv[jj] == sv[i]) ? 1 : 0;
            }
            rank[g][i] = r;
            psort[g][r] = sv[i];
        }
        psort[g][0] = 0.0f; psort[g][3] = 63.0f;
        float p1 = psort[g][1], p2 = psort[g][2];
        float g1 = p1, g2 = p2 - p1, g3 = 63.0f - p2;
        const float MG = 10.5f;
        float r1 = fmaxf(MG - g1, 0.f), r2 = fmaxf(MG - g2, 0.f), r3 = fmaxf(MG - g3, 0.f);
        float sp = (r1*r1 + r2*r2 + r3*r3) * (1.0f / 3.0f);
        float l0 = mlsh[g][0], l1 = mlsh[g][1];
        float m = fmaxf(l0, l1);
        float e0 = __expf(l0 - m), e1 = __expf(l1 - m);
        float inv = 1.0f / (e0 + e1);
        float q0 = e0 * inv, q1 = e1 * inv;
        qsh[g][0] = q0; qsh[g][1] = q1;
        float entc = q0 * logf(q0 + 1e-8f) + q1 * logf(q1 + 1e-8f);
        atomicAdd(&accums[2], entc);
        atomicAdd(&accums[3], q0);
        atomicAdd(&accums[4], q1);
        atomicAdd(&accums[5], sp);
    }
    __syncthreads();

    // scatter anchor vals into sorted order
    #pragma unroll
    for (int u2 = 0; u2 < 8; ++u2){
        int idx2 = tid * 8 + u2;
        int g = idx2 >> 7, j = idx2 & 127;
        avs[g * 132 + rank[g][j >> 5] * 32 + (j & 31)] = av[g * 132 + j];
    }
    __syncthreads();

    // stage D: residual GEMM (N=2048) streamed into interp + recon + losses
    float lsq = 0.f, ll1 = 0.f;
    const float* Arow = A + (size_t)b0 * 2048;
    for (int c = 0; c < 8; ++c){
        f32x4 acc[4];
        #pragma unroll
        for (int nt = 0; nt < 4; ++nt) acc[nt] = (f32x4){0.f,0.f,0.f,0.f};
        int ntg0 = (w << 5) + (c << 2);
        #pragma unroll
        for (int kk = 0; kk < 8; ++kk){
            bf16x8 af = *(const bf16x8*)&rhb[l15 * AS + (kk << 5) + q8];
            #pragma unroll
            for (int nt = 0; nt < 4; ++nt){
                bf16x8 bfr = *(const bf16x8*)(pk + O_RES2 + (size_t)((((kk << 7) + ntg0 + nt) << 6) + lane) * 8);
                acc[nt] = __builtin_amdgcn_mfma_f32_16x16x32_bf16(af, bfr, acc[nt], 0, 0, 0);
            }
        }
        int e0 = (w << 9) + (c << 6);
        #pragma unroll
        for (int nt = 0; nt < 4; ++nt){
            int e = e0 + (nt << 4) + l15;
            float rbv = res_b2[e];
            int t = e >> 5, d = e & 31;
            float tf = (float)t;
            #pragma unroll
            for (int r = 0; r < 4; ++r){
                int g = q4 + r;
                float res = acc[nt][r] + rbv;
                float p1 = psort[g][1], p2 = psort[g][2];
                int cnt = (p1 <= tf) + (p2 <= tf) + (tf >= 63.0f);
                int idx = cnt < 2 ? cnt : 2;
                float left  = idx == 0 ? 0.0f : (idx == 1 ? p1 : p2);
                float right = idx == 0 ? p1   : (idx == 1 ? p2 : 63.0f);
                float wgt = (tf - left) / (right - left + 1e-8f);
                wgt = fminf(fmaxf(wgt, 0.f), 1.f);
                float vl = avs[g * 132 + idx * 32 + d];
                float vr = avs[g * 132 + idx * 32 + 32 + d];
                float coarse = vl + wgt * (vr - vl);
                float a = Arow[(size_t)g * 2048 + e];
                float fine = coarse + res;
                float recon = qsh[g][0] * coarse + qsh[g][1] * fine;
                float dd = recon - a;
                lsq += dd * dd;
                ll1 += fabsf(res);
            }
        }
    }
    #pragma unroll
    for (int off = 32; off > 0; off >>= 1){
        lsq += __shfl_down(lsq, off);
        ll1 += __shfl_down(ll1, off);
    }
    if (lane == 0){ wred[w] = lsq; wred2[w] = ll1; }
    __syncthreads();
    if (tid == 0){
        atomicAdd(&accums[0], wred[0] + wred[1] + wred[2] + wred[3]);
        atomicAdd(&accums[1], wred2[0] + wred2[1] + wred2[2] + wred2[3]);
    }
}

// ---------------- Kernel 3: finalize ----------------
__global__ void finalize_kernel(const float* __restrict__ accums, float* __restrict__ out){
    float rs = accums[0], l1s = accums[1], ents = accums[2];
    float q0s = accums[3], q1s = accums[4], sps = accums[5];
    const float invN = 1.0f / (4096.0f * 2048.0f);
    const float invB = 1.0f / 4096.0f;
    float recon_loss = rs * invN;
    float l1   = l1s * invN;
    float ent  = -ents * invB;
    float mq0  = q0s * invB - 0.5f, mq1 = q1s * invB - 0.5f;
    float balance = mq0*mq0 + mq1*mq1;
    float spacing = sps * invB;
    out[0] = recon_loss + 0.05f*l1 + 0.01f*ent + 0.1f*balance + 0.1f*spacing;
}

extern "C" void kernel_launch(void* const* d_in, const int* in_sizes, int n_in,
                              void* d_out, int out_size, void* d_ws, size_t ws_size,
                              hipStream_t stream)
{
    const float* A      = (const float*)d_in[0];
    const float* W0     = (const float*)d_in[1];
    const float* B0     = (const float*)d_in[2];
    const float* W1     = (const float*)d_in[3];
    const float* B1     = (const float*)d_in[4];
    const float* W2     = (const float*)d_in[5];
    const float* B2     = (const float*)d_in[6];
    const float* proj_w = (const float*)d_in[7];
    const float* proj_b = (const float*)d_in[8];
    const float* val_w1 = (const float*)d_in[9];
    const float* val_b1 = (const float*)d_in[10];
    const float* val_w2 = (const float*)d_in[11];
    const float* val_b2 = (const float*)d_in[12];
    const float* pos_w1 = (const float*)d_in[13];
    const float* pos_b1 = (const float*)d_in[14];
    const float* pos_w2 = (const float*)d_in[15];
    const float* pos_b2 = (const float*)d_in[16];
    const float* res_w1 = (const float*)d_in[17];
    const float* res_b1 = (const float*)d_in[18];
    const float* res_w2 = (const float*)d_in[19];
    const float* res_b2 = (const float*)d_in[20];
    const float* mix_w  = (const float*)d_in[21];
    const float* mix_b  = (const float*)d_in[22];

    float* accums = (float*)d_ws;
    float* pooled = (float*)d_ws + 64;
    unsigned short* pkbuf = (unsigned short*)((char*)d_ws + (size_t)(64 + 4096*256) * 4);

    hipMemsetAsync(accums, 0, 64 * sizeof(float), stream);

    hipLaunchKernelGGL(pack_weights, dim3((PK_TOTAL + 255) / 256), dim3(256), 0, stream,
                       W0, W1, W2, proj_w, val_w1, pos_w1, res_w1,
                       val_w2, res_w2, pos_w2, mix_w, pkbuf);

    hipLaunchKernelGGL(conv_mfma_kernel, dim3(NB), dim3(256), 0, stream,
                       A, B0, B1, B2,
                       pkbuf + O_WP0, pkbuf + O_WP1, pkbuf + O_WP2, pooled);

    hipLaunchKernelGGL(heads_mfma_kernel, dim3(NB/16), dim3(256), 0, stream,
                       A, pooled,
                       proj_b, val_b1, pos_b1, res_b1, val_b2, pos_b2, res_b2, mix_b,
                       pkbuf, accums);

    hipLaunchKernelGGL(finalize_kernel, dim3(1), dim3(1), 0, stream,
                       accums, (float*)d_out);
}

// Round 4
// 563.870 us; speedup vs baseline: 9.4146x; 1.0656x over previous
//
#include <hip/hip_runtime.h>

#define NB 4096

typedef __attribute__((ext_vector_type(8))) __bf16 bf16x8;
typedef __attribute__((ext_vector_type(4))) float  f32x4;

__device__ __forceinline__ float gelu_fast(float x){
    float x2 = x * x;
    float y  = x * (0.79788456f + 0.03567741f * x2);
    float e  = __expf(2.0f * y);
    float t  = 1.0f - 2.0f / (e + 1.0f);
    return 0.5f * x * (1.0f + t);
}
__device__ __forceinline__ unsigned short f2bf(float x){
    unsigned b = __float_as_uint(x);
    b += 0x7fffu + ((b >> 16) & 1u);
    return (unsigned short)(b >> 16);
}

// ---------------- pack offsets (elements) ----------------
#define O_WP0  0
#define O_WP1  40960
#define O_WP2  368640
#define O_PROJ 696320
#define O_VAL1 761856
#define O_POS1 827392
#define O_RES1 892928
#define O_VAL2 958464
#define O_RES2 991232
#define O_POS2 1515520
#define O_MIX  1519616
#define PK_TOTAL 1523712

__device__ __forceinline__ unsigned short pack_std_elem(const float* W, int N, int t){
    int j = t & 7, lane = (t >> 3) & 63, rest = t >> 9;
    int ntcnt = N >> 4;
    int nt = rest % ntcnt, kk = rest / ntcnt;
    int n = nt*16 + (lane & 15), k = kk*32 + ((lane >> 4) << 3) + j;
    return f2bf(W[k * N + n]);
}
__device__ __forceinline__ unsigned short pack_pad_elem(const float* W, int Nreal, int t){
    int j = t & 7, lane = (t >> 3) & 63, kk = t >> 9;
    int n = lane & 15, k = kk*32 + ((lane >> 4) << 3) + j;
    return (n < Nreal) ? f2bf(W[k * Nreal + n]) : (unsigned short)0;
}

__global__ __launch_bounds__(256) void pack_weights(
    const float* __restrict__ W0, const float* __restrict__ W1, const float* __restrict__ W2,
    const float* __restrict__ proj_w, const float* __restrict__ val_w1,
    const float* __restrict__ pos_w1, const float* __restrict__ res_w1,
    const float* __restrict__ val_w2, const float* __restrict__ res_w2,
    const float* __restrict__ pos_w2, const float* __restrict__ mix_w,
    unsigned short* __restrict__ pk)
{
    int idx = blockIdx.x * 256 + threadIdx.x;
    if (idx >= PK_TOTAL) return;
    if (idx < O_WP1){
        int t = idx;
        int j = t & 7, lane = (t >> 3) & 63, gnt = (t >> 9) & 15, kk = t >> 13;
        int co = gnt*16 + (lane & 15), ci = (lane >> 4)*8 + j;
        pk[idx] = f2bf(W0[co*160 + ci*5 + kk]);
    } else if (idx < O_WP2){
        int t = idx - O_WP1;
        int j = t & 7, lane = (t >> 3) & 63, gnt = (t >> 9) & 15, kk = t >> 13;
        int kc = kk >> 3, s = kk & 7;
        int co = gnt*16 + (lane & 15), ci = s*32 + (lane >> 4)*8 + j;
        pk[idx] = f2bf(W1[co*1280 + ci*5 + kc]);
    } else if (idx < O_PROJ){
        int t = idx - O_WP2;
        int j = t & 7, lane = (t >> 3) & 63, gnt = (t >> 9) & 15, kk = t >> 13;
        int kc = kk >> 3, s = kk & 7;
        int co = gnt*16 + (lane & 15), ci = s*32 + (lane >> 4)*8 + j;
        pk[idx] = f2bf(W2[co*1280 + ci*5 + kc]);
    }
    else if (idx < O_VAL1) pk[idx] = pack_std_elem(proj_w, 256, idx - O_PROJ);
    else if (idx < O_POS1) pk[idx] = pack_std_elem(val_w1, 256, idx - O_VAL1);
    else if (idx < O_RES1) pk[idx] = pack_std_elem(pos_w1, 256, idx - O_POS1);
    else if (idx < O_VAL2) pk[idx] = pack_std_elem(res_w1, 256, idx - O_RES1);
    else if (idx < O_RES2) pk[idx] = pack_std_elem(val_w2, 128, idx - O_VAL2);
    else if (idx < O_POS2) pk[idx] = pack_std_elem(res_w2, 2048, idx - O_RES2);
    else if (idx < O_MIX)  pk[idx] = pack_pad_elem(pos_w2, 4, idx - O_POS2);
    else                   pk[idx] = pack_pad_elem(mix_w, 2, idx - O_MIX);
}

// ---------------- Kernel 1: MFMA conv, 2 batches per block ----------------
#define HT_S 264
#define XT_S 32

__global__ __launch_bounds__(256, 2) void conv_mfma_kernel(
    const float* __restrict__ A,
    const float* __restrict__ B0, const float* __restrict__ B1, const float* __restrict__ B2,
    const unsigned short* __restrict__ wp0, const unsigned short* __restrict__ wp1,
    const unsigned short* __restrict__ wp2,
    unsigned short* __restrict__ pooled)
{
    __shared__ unsigned short xt[2][68 * XT_S];   // 8704 B
    __shared__ unsigned short ht[2][68 * HT_S];   // 71808 B  (total 80512 <= 80KB -> 2 blocks/CU)

    const int tid  = threadIdx.x;
    const int b0   = blockIdx.x * 2;
    const int w    = tid >> 6;
    const int lane = tid & 63;
    const int l15  = lane & 15;
    const int q    = lane >> 4;
    const int w4   = w << 2;
    const int w64  = w << 6;
    const int q8   = q << 3;
    const int q4   = q << 2;
    const int lane8 = lane << 3;

    // zero halo rows
    for (int i = tid; i < 4 * HT_S; i += 256){
        int r = i / HT_S, c = i - r * HT_S;
        int rr = (r < 2 ? r : r + 64);
        ht[0][rr * HT_S + c] = 0;
        ht[1][rr * HT_S + c] = 0;
    }
    if (tid < 128){
        int r = tid >> 5, c = tid & 31;
        int rr = (r < 2 ? r : r + 64);
        xt[0][rr * XT_S + c] = 0;
        xt[1][rr * XT_S + c] = 0;
    }
    // stage inputs
    #pragma unroll
    for (int bb = 0; bb < 2; ++bb){
        const float* Ab = A + (size_t)(b0 + bb) * 2048;
        int e0 = tid << 3;
        int t = e0 >> 5, c = e0 & 31;
        const float4* p = (const float4*)(Ab + e0);
        float4 v0 = p[0], v1 = p[1];
        union { unsigned short u[8]; bf16x8 v; } pkv;
        pkv.u[0]=f2bf(v0.x); pkv.u[1]=f2bf(v0.y); pkv.u[2]=f2bf(v0.z); pkv.u[3]=f2bf(v0.w);
        pkv.u[4]=f2bf(v1.x); pkv.u[5]=f2bf(v1.y); pkv.u[6]=f2bf(v1.z); pkv.u[7]=f2bf(v1.w);
        *(bf16x8*)&xt[bb][(t + 2) * XT_S + c] = pkv.v;
    }
    __syncthreads();

    f32x4 acc0[4][4], acc1[4][4];

#define ZERO2 \
    { _Pragma("unroll") for (int mt = 0; mt < 4; ++mt) \
      _Pragma("unroll") for (int nt = 0; nt < 4; ++nt){ \
          acc0[mt][nt] = (f32x4){0.f,0.f,0.f,0.f}; acc1[mt][nt] = (f32x4){0.f,0.f,0.f,0.f}; } }
#define LOADA_X(BUF, BB, KC) \
    { _Pragma("unroll") for (int mt = 0; mt < 4; ++mt) \
          BUF[mt] = *(const bf16x8*)&xt[BB][((mt << 4) + l15 + (KC)) * XT_S + q8]; }
#define LOADA_H(BUF, BB, KK) \
    { _Pragma("unroll") for (int mt = 0; mt < 4; ++mt) \
          BUF[mt] = *(const bf16x8*)&ht[BB][((mt << 4) + l15 + ((KK) >> 3)) * HT_S + (((KK) & 7) << 5) + q8]; }
#define LOADB_(BUF, KK, WP) \
    { _Pragma("unroll") for (int nt = 0; nt < 4; ++nt) \
          BUF[nt] = *(const bf16x8*)((WP) + ((((KK) << 4) + w4 + nt) << 9) + lane8); }
#define MF(ACC, AB, BB_) \
    { _Pragma("unroll") for (int mt = 0; mt < 4; ++mt) \
      _Pragma("unroll") for (int nt = 0; nt < 4; ++nt) \
          ACC[mt][nt] = __builtin_amdgcn_mfma_f32_16x16x32_bf16(AB[mt], BB_[nt], ACC[mt][nt], 0, 0, 0); }
#define EPI(ACC, BB, BIAS) \
    { float bv[4]; \
      _Pragma("unroll") for (int nt = 0; nt < 4; ++nt) bv[nt] = (BIAS)[w64 + (nt << 4) + l15]; \
      _Pragma("unroll") for (int mt = 0; mt < 4; ++mt) \
      _Pragma("unroll") for (int nt = 0; nt < 4; ++nt) \
      _Pragma("unroll") for (int r = 0; r < 4; ++r){ \
          float v = gelu_fast(ACC[mt][nt][r] + bv[nt]); \
          ht[BB][((mt << 4) + q4 + r + 2) * HT_S + w64 + (nt << 4) + l15] = f2bf(v); } }
#define CONV_LAYER2(WP) \
    { bf16x8 Af[4], Bf[4]; \
      _Pragma("unroll 4") \
      for (int kk = 0; kk < 40; ++kk){ \
          LOADB_(Bf, kk, WP); \
          LOADA_H(Af, 0, kk); MF(acc0, Af, Bf); \
          LOADA_H(Af, 1, kk); MF(acc1, Af, Bf); } }

    // ---- conv0 ----
    ZERO2;
    #pragma unroll
    for (int kc = 0; kc < 5; ++kc){
        bf16x8 Af[4], Bf[4];
        LOADB_(Bf, kc, wp0);
        LOADA_X(Af, 0, kc); MF(acc0, Af, Bf);
        LOADA_X(Af, 1, kc); MF(acc1, Af, Bf);
    }
    EPI(acc0, 0, B0);
    EPI(acc1, 1, B0);
    __syncthreads();

    // ---- conv1 ----
    ZERO2;
    CONV_LAYER2(wp1);
    __syncthreads();
    EPI(acc0, 0, B1);
    EPI(acc1, 1, B1);
    __syncthreads();

    // ---- conv2 + mean pool ----
    ZERO2;
    CONV_LAYER2(wp2);
    {
        float bv[4];
        #pragma unroll
        for (int nt = 0; nt < 4; ++nt) bv[nt] = B2[w64 + (nt << 4) + l15];
        #pragma unroll
        for (int bb = 0; bb < 2; ++bb){
            float s[4];
            #pragma unroll
            for (int nt = 0; nt < 4; ++nt){
                float acc_s = 0.f;
                #pragma unroll
                for (int mt = 0; mt < 4; ++mt)
                    #pragma unroll
                    for (int r = 0; r < 4; ++r){
                        float v = bb == 0 ? acc0[mt][nt][r] : acc1[mt][nt][r];
                        acc_s += gelu_fast(v + bv[nt]);
                    }
                s[nt] = acc_s;
            }
            #pragma unroll
            for (int nt = 0; nt < 4; ++nt){
                s[nt] += __shfl_xor(s[nt], 16);
                s[nt] += __shfl_xor(s[nt], 32);
            }
            if (q == 0){
                #pragma unroll
                for (int nt = 0; nt < 4; ++nt)
                    pooled[(size_t)(b0 + bb) * 256 + w64 + (nt << 4) + l15] = f2bf(s[nt] * (1.0f / 64.0f));
            }
        }
    }
}

// ---------------- Kernel 2a: heads stages A-C, 16 batches/block ----------------
#define AS 264

__global__ __launch_bounds__(256) void heads_a_kernel(
    const unsigned short* __restrict__ pooled,
    const float* __restrict__ proj_b, const float* __restrict__ val_b1,
    const float* __restrict__ pos_b1, const float* __restrict__ res_b1,
    const float* __restrict__ val_b2, const float* __restrict__ pos_b2,
    const float* __restrict__ mix_b,
    const unsigned short* __restrict__ pk,
    unsigned short* __restrict__ rh, float* __restrict__ meta,
    float* __restrict__ accums)
{
    __shared__ unsigned short pb [16 * AS];
    __shared__ unsigned short eb [16 * AS];
    __shared__ unsigned short vb [16 * AS];
    __shared__ unsigned short phb[16 * AS];
    __shared__ unsigned short rhb[16 * AS];
    __shared__ float av [16 * 132];
    __shared__ float avs[16 * 132];
    __shared__ float psort[16][4];
    __shared__ int   rank [16][4];
    __shared__ float qsh  [16][2];
    __shared__ float mlsh [16][2];
    __shared__ float sposh[16][4];

    const int tid  = threadIdx.x;
    const int b0   = blockIdx.x * 16;
    const int w    = tid >> 6;
    const int lane = tid & 63;
    const int l15  = lane & 15;
    const int q    = lane >> 4;
    const int q8   = q << 3;
    const int q4   = q << 2;

    // stage pooled (bf16) -> pb
    {
        int g = tid >> 4, seg = tid & 15;
        const unsigned short* ps = pooled + ((size_t)(b0 + g) << 8) + (seg << 4);
        bf16x8 a0 = *(const bf16x8*)ps;
        bf16x8 a1 = *(const bf16x8*)(ps + 8);
        *(bf16x8*)&pb[g * AS + (seg << 4)]     = a0;
        *(bf16x8*)&pb[g * AS + (seg << 4) + 8] = a1;
    }
    __syncthreads();

#define HGEMM256(ASRC, GOFF, BIAS, DST) \
    { f32x4 hacc[4]; \
      _Pragma("unroll") for (int nt = 0; nt < 4; ++nt) hacc[nt] = (f32x4){0.f,0.f,0.f,0.f}; \
      _Pragma("unroll") for (int kk = 0; kk < 8; ++kk){ \
          bf16x8 af = *(const bf16x8*)&(ASRC)[l15 * AS + (kk << 5) + q8]; \
          _Pragma("unroll") for (int nt = 0; nt < 4; ++nt){ \
              bf16x8 bfr = *(const bf16x8*)(pk + (GOFF) + (size_t)((((kk << 4) + (w << 2) + nt) << 6) + lane) * 8); \
              hacc[nt] = __builtin_amdgcn_mfma_f32_16x16x32_bf16(af, bfr, hacc[nt], 0, 0, 0); } } \
      _Pragma("unroll") for (int nt = 0; nt < 4; ++nt){ \
          int n = (w << 6) + (nt << 4) + l15; \
          float bv = (BIAS)[n]; \
          _Pragma("unroll") for (int r = 0; r < 4; ++r) \
              (DST)[(q4 + r) * AS + n] = f2bf(gelu_fast(hacc[nt][r] + bv)); } }

    HGEMM256(pb, O_PROJ, proj_b, eb);
    __syncthreads();

    HGEMM256(eb, O_VAL1, val_b1, vb);
    HGEMM256(eb, O_POS1, pos_b1, phb);
    HGEMM256(eb, O_RES1, res_b1, rhb);
    __syncthreads();

    // stage C: anchor vals (N=128), pos head (wave0), mix head (wave1)
    {
        f32x4 acc2[2];
        #pragma unroll
        for (int nt = 0; nt < 2; ++nt) acc2[nt] = (f32x4){0.f,0.f,0.f,0.f};
        #pragma unroll
        for (int kk = 0; kk < 8; ++kk){
            bf16x8 af = *(const bf16x8*)&vb[l15 * AS + (kk << 5) + q8];
            #pragma unroll
            for (int nt = 0; nt < 2; ++nt){
                bf16x8 bfr = *(const bf16x8*)(pk + O_VAL2 + (size_t)(((kk*8 + w*2 + nt) << 6) + lane) * 8);
                acc2[nt] = __builtin_amdgcn_mfma_f32_16x16x32_bf16(af, bfr, acc2[nt], 0, 0, 0);
            }
        }
        #pragma unroll
        for (int nt = 0; nt < 2; ++nt){
            int j = (w << 5) + (nt << 4) + l15;
            float bv = val_b2[j];
            #pragma unroll
            for (int r = 0; r < 4; ++r)
                av[(q4 + r) * 132 + j] = acc2[nt][r] + bv;
        }
    }
    if (w == 0){
        f32x4 accp = (f32x4){0.f,0.f,0.f,0.f};
        #pragma unroll
        for (int kk = 0; kk < 8; ++kk){
            bf16x8 af  = *(const bf16x8*)&phb[l15 * AS + (kk << 5) + q8];
            bf16x8 bfr = *(const bf16x8*)(pk + O_POS2 + (size_t)((kk << 6) + lane) * 8);
            accp = __builtin_amdgcn_mfma_f32_16x16x32_bf16(af, bfr, accp, 0, 0, 0);
        }
        if (l15 < 4){
            float bv = pos_b2[l15];
            #pragma unroll
            for (int r = 0; r < 4; ++r){
                float raw = accp[r] + bv;
                sposh[q4 + r][l15] = 63.0f / (1.0f + __expf(-raw));
            }
        }
    } else if (w == 1){
        f32x4 accm = (f32x4){0.f,0.f,0.f,0.f};
        #pragma unroll
        for (int kk = 0; kk < 8; ++kk){
            bf16x8 af  = *(const bf16x8*)&eb[l15 * AS + (kk << 5) + q8];
            bf16x8 bfr = *(const bf16x8*)(pk + O_MIX + (size_t)((kk << 6) + lane) * 8);
            accm = __builtin_amdgcn_mfma_f32_16x16x32_bf16(af, bfr, accm, 0, 0, 0);
        }
        if (l15 < 2){
            #pragma unroll
            for (int r = 0; r < 4; ++r)
                mlsh[q4 + r][l15] = accm[r] + mix_b[l15];
        }
    }
    __syncthreads();

    // sort + spacing + softmax + entropy
    if (tid < 16){
        int g = tid;
        float sv[4] = { sposh[g][0], sposh[g][1], sposh[g][2], sposh[g][3] };
        #pragma unroll
        for (int i = 0; i < 4; ++i){
            int r = 0;
            #pragma unroll
            for (int jj = 0; jj < 4; ++jj){
                r += (sv[jj] < sv[i]) ? 1 : 0;
                if (jj < i) r += (sv[jj] == sv[i]) ? 1 : 0;
            }
            rank[g][i] = r;
            psort[g][r] = sv[i];
        }
        psort[g][0] = 0.0f; psort[g][3] = 63.0f;
        float p1 = psort[g][1], p2 = psort[g][2];
        float g1 = p1, g2 = p2 - p1, g3 = 63.0f - p2;
        const float MG = 10.5f;
        float r1 = fmaxf(MG - g1, 0.f), r2 = fmaxf(MG - g2, 0.f), r3 = fmaxf(MG - g3, 0.f);
        float sp = (r1*r1 + r2*r2 + r3*r3) * (1.0f / 3.0f);
        float l0 = mlsh[g][0], l1 = mlsh[g][1];
        float m = fmaxf(l0, l1);
        float e0 = __expf(l0 - m), e1 = __expf(l1 - m);
        float inv = 1.0f / (e0 + e1);
        float q0 = e0 * inv, q1 = e1 * inv;
        qsh[g][0] = q0; qsh[g][1] = q1;
        float entc = q0 * logf(q0 + 1e-8f) + q1 * logf(q1 + 1e-8f);
        atomicAdd(&accums[2], entc);
        atomicAdd(&accums[3], q0);
        atomicAdd(&accums[4], q1);
        atomicAdd(&accums[5], sp);
    }
    __syncthreads();

    // scatter anchor vals into sorted order
    #pragma unroll
    for (int u2 = 0; u2 < 8; ++u2){
        int idx2 = tid * 8 + u2;
        int g = idx2 >> 7, j = idx2 & 127;
        avs[g * 132 + rank[g][j >> 5] * 32 + (j & 31)] = av[g * 132 + j];
    }
    __syncthreads();

    // write rh (bf16) and meta
    {
        int g = tid >> 4, c16 = (tid & 15) << 4;
        bf16x8 a0 = *(const bf16x8*)&rhb[g * AS + c16];
        bf16x8 a1 = *(const bf16x8*)&rhb[g * AS + c16 + 8];
        unsigned short* dst = rh + ((size_t)(b0 + g) << 8) + c16;
        *(bf16x8*)dst       = a0;
        *(bf16x8*)(dst + 8) = a1;
    }
    if (tid < 132){
        for (int g = 0; g < 16; ++g){
            float v;
            if (tid < 128)       v = avs[g * 132 + tid];
            else if (tid == 128) v = psort[g][1];
            else if (tid == 129) v = psort[g][2];
            else if (tid == 130) v = qsh[g][0];
            else                 v = qsh[g][1];
            meta[(size_t)(b0 + g) * 132 + tid] = v;
        }
    }
}

// ---------------- Kernel 2b: residual GEMM + interp + recon/L1 losses ----------------
// grid = 1024: 256 batch-groups x 4 col-chunks of 512
__global__ __launch_bounds__(256) void resid_loss_kernel(
    const float* __restrict__ A, const unsigned short* __restrict__ rh,
    const float* __restrict__ res_b2, const unsigned short* __restrict__ pk,
    const float* __restrict__ meta, float* __restrict__ accums)
{
    __shared__ float ml[16 * 132];
    __shared__ float wred[4], wred2[4];

    const int tid  = threadIdx.x;
    const int w    = tid >> 6;
    const int lane = tid & 63;
    const int l15  = lane & 15;
    const int q    = lane >> 4;
    const int q8   = q << 3;
    const int q4   = q << 2;
    const int bg   = blockIdx.x >> 2;
    const int cc   = blockIdx.x & 3;
    const int b0   = bg << 4;

    for (int i = tid; i < 16 * 132; i += 256)
        ml[i] = meta[(size_t)b0 * 132 + i];
    __syncthreads();

    f32x4 acc[8];
    #pragma unroll
    for (int nt = 0; nt < 8; ++nt) acc[nt] = (f32x4){0.f,0.f,0.f,0.f};
    #pragma unroll
    for (int kk = 0; kk < 8; ++kk){
        bf16x8 af = *(const bf16x8*)(rh + ((size_t)(b0 + l15) << 8) + (kk << 5) + q8);
        #pragma unroll
        for (int nt = 0; nt < 8; ++nt){
            int ntg = (cc << 5) + (w << 3) + nt;
            bf16x8 bfr = *(const bf16x8*)(pk + O_RES2 + (size_t)((kk << 7) + ntg) * 512 + (lane << 3));
            acc[nt] = __builtin_amdgcn_mfma_f32_16x16x32_bf16(af, bfr, acc[nt], 0, 0, 0);
        }
    }

    float lsq = 0.f, ll1 = 0.f;
    #pragma unroll
    for (int nt = 0; nt < 8; ++nt){
        int e = (cc << 9) + (w << 7) + (nt << 4) + l15;
        float rbv = res_b2[e];
        int t = e >> 5, d = e & 31;
        float tf = (float)t;
        #pragma unroll
        for (int r = 0; r < 4; ++r){
            int g = q4 + r;
            const float* mg = &ml[g * 132];
            float p1 = mg[128], p2 = mg[129], q0 = mg[130], q1 = mg[131];
            float res = acc[nt][r] + rbv;
            int cnt = (p1 <= tf) + (p2 <= tf) + (tf >= 63.0f);
            int idx = cnt < 2 ? cnt : 2;
            float left  = idx == 0 ? 0.0f : (idx == 1 ? p1 : p2);
            float right = idx == 0 ? p1   : (idx == 1 ? p2 : 63.0f);
            float wgt = (tf - left) / (right - left + 1e-8f);
            wgt = fminf(fmaxf(wgt, 0.f), 1.f);
            float vl = mg[idx * 32 + d];
            float vr = mg[idx * 32 + 32 + d];
            float coarse = vl + wgt * (vr - vl);
            float a = A[((size_t)(b0 + g) << 11) + e];
            float fine = coarse + res;
            float recon = q0 * coarse + q1 * fine;
            float dd = recon - a;
            lsq += dd * dd;
            ll1 += fabsf(res);
        }
    }
    #pragma unroll
    for (int off = 32; off > 0; off >>= 1){
        lsq += __shfl_down(lsq, off);
        ll1 += __shfl_down(ll1, off);
    }
    if (lane == 0){ wred[w] = lsq; wred2[w] = ll1; }
    __syncthreads();
    if (tid == 0){
        atomicAdd(&accums[0], wred[0] + wred[1] + wred[2] + wred[3]);
        atomicAdd(&accums[1], wred2[0] + wred2[1] + wred2[2] + wred2[3]);
    }
}

// ---------------- Kernel 3: finalize ----------------
__global__ void finalize_kernel(const float* __restrict__ accums, float* __restrict__ out){
    float rs = accums[0], l1s = accums[1], ents = accums[2];
    float q0s = accums[3], q1s = accums[4], sps = accums[5];
    const float invN = 1.0f / (4096.0f * 2048.0f);
    const float invB = 1.0f / 4096.0f;
    float recon_loss = rs * invN;
    float l1   = l1s * invN;
    float ent  = -ents * invB;
    float mq0  = q0s * invB - 0.5f, mq1 = q1s * invB - 0.5f;
    float balance = mq0*mq0 + mq1*mq1;
    float spacing = sps * invB;
    out[0] = recon_loss + 0.05f*l1 + 0.01f*ent + 0.1f*balance + 0.1f*spacing;
}

extern "C" void kernel_launch(void* const* d_in, const int* in_sizes, int n_in,
                              void* d_out, int out_size, void* d_ws, size_t ws_size,
                              hipStream_t stream)
{
    const float* A      = (const float*)d_in[0];
    const float* W0     = (const float*)d_in[1];
    const float* B0     = (const float*)d_in[2];
    const float* W1     = (const float*)d_in[3];
    const float* B1     = (const float*)d_in[4];
    const float* W2     = (const float*)d_in[5];
    const float* B2     = (const float*)d_in[6];
    const float* proj_w = (const float*)d_in[7];
    const float* proj_b = (const float*)d_in[8];
    const float* val_w1 = (const float*)d_in[9];
    const float* val_b1 = (const float*)d_in[10];
    const float* val_w2 = (const float*)d_in[11];
    const float* val_b2 = (const float*)d_in[12];
    const float* pos_w1 = (const float*)d_in[13];
    const float* pos_b1 = (const float*)d_in[14];
    const float* pos_w2 = (const float*)d_in[15];
    const float* pos_b2 = (const float*)d_in[16];
    const float* res_w1 = (const float*)d_in[17];
    const float* res_b1 = (const float*)d_in[18];
    const float* res_w2 = (const float*)d_in[19];
    const float* res_b2 = (const float*)d_in[20];
    const float* mix_w  = (const float*)d_in[21];
    const float* mix_b  = (const float*)d_in[22];

    // ws layout (bytes):
    //   [0,256)                     accums
    //   [256, 256+2MB)              pooled bf16 (4096x256)
    //   [.., +PK_TOTAL*2)           packed weights
    //   [.., +2MB)                  rh bf16 (4096x256)
    //   [.., +4096*132*4)           meta f32
    char* wsb = (char*)d_ws;
    float* accums = (float*)wsb;
    unsigned short* pooled = (unsigned short*)(wsb + 256);
    unsigned short* pkbuf  = (unsigned short*)(wsb + 256 + 2097152);
    unsigned short* rhbuf  = (unsigned short*)(wsb + 256 + 2097152 + (size_t)PK_TOTAL * 2);
    float* metabuf = (float*)(wsb + 256 + 2097152 + (size_t)PK_TOTAL * 2 + 2097152);

    hipMemsetAsync(accums, 0, 64 * sizeof(float), stream);

    hipLaunchKernelGGL(pack_weights, dim3((PK_TOTAL + 255) / 256), dim3(256), 0, stream,
                       W0, W1, W2, proj_w, val_w1, pos_w1, res_w1,
                       val_w2, res_w2, pos_w2, mix_w, pkbuf);

    hipLaunchKernelGGL(conv_mfma_kernel, dim3(NB / 2), dim3(256), 0, stream,
                       A, B0, B1, B2,
                       pkbuf + O_WP0, pkbuf + O_WP1, pkbuf + O_WP2, pooled);

    hipLaunchKernelGGL(heads_a_kernel, dim3(NB / 16), dim3(256), 0, stream,
                       pooled, proj_b, val_b1, pos_b1, res_b1, val_b2, pos_b2, mix_b,
                       pkbuf, rhbuf, metabuf, accums);

    hipLaunchKernelGGL(resid_loss_kernel, dim3(NB / 16 * 4), dim3(256), 0, stream,
                       A, rhbuf, res_b2, pkbuf, metabuf, accums);

    hipLaunchKernelGGL(finalize_kernel, dim3(1), dim3(1), 0, stream,
                       accums, (float*)d_out);
}

// Round 5
// 548.260 us; speedup vs baseline: 9.6826x; 1.0285x over previous
//
#include <hip/hip_runtime.h>

#define NB 4096

typedef __attribute__((ext_vector_type(8))) __bf16 bf16x8;
typedef __attribute__((ext_vector_type(4))) float  f32x4;

__device__ __forceinline__ float gelu_fast(float x){
    float x2 = x * x;
    float y  = x * (0.79788456f + 0.03567741f * x2);
    float e  = __expf(2.0f * y);
    float t  = 1.0f - 2.0f / (e + 1.0f);
    return 0.5f * x * (1.0f + t);
}
__device__ __forceinline__ unsigned short f2bf(float x){
    unsigned b = __float_as_uint(x);
    b += 0x7fffu + ((b >> 16) & 1u);
    return (unsigned short)(b >> 16);
}

// ---------------- pack offsets (elements) ----------------
#define O_WP0  0
#define O_WP1  40960
#define O_WP2  368640
#define O_PROJ 696320
#define O_VAL1 761856
#define O_POS1 827392
#define O_RES1 892928
#define O_VAL2 958464
#define O_RES2 991232
#define O_POS2 1515520
#define O_MIX  1519616
#define PK_TOTAL 1523712

__device__ __forceinline__ unsigned short pack_std_elem(const float* W, int N, int t){
    int j = t & 7, lane = (t >> 3) & 63, rest = t >> 9;
    int ntcnt = N >> 4;
    int nt = rest % ntcnt, kk = rest / ntcnt;
    int n = nt*16 + (lane & 15), k = kk*32 + ((lane >> 4) << 3) + j;
    return f2bf(W[k * N + n]);
}
__device__ __forceinline__ unsigned short pack_pad_elem(const float* W, int Nreal, int t){
    int j = t & 7, lane = (t >> 3) & 63, kk = t >> 9;
    int n = lane & 15, k = kk*32 + ((lane >> 4) << 3) + j;
    return (n < Nreal) ? f2bf(W[k * Nreal + n]) : (unsigned short)0;
}

__global__ __launch_bounds__(256) void pack_weights(
    const float* __restrict__ W0, const float* __restrict__ W1, const float* __restrict__ W2,
    const float* __restrict__ proj_w, const float* __restrict__ val_w1,
    const float* __restrict__ pos_w1, const float* __restrict__ res_w1,
    const float* __restrict__ val_w2, const float* __restrict__ res_w2,
    const float* __restrict__ pos_w2, const float* __restrict__ mix_w,
    unsigned short* __restrict__ pk)
{
    int idx = blockIdx.x * 256 + threadIdx.x;
    if (idx >= PK_TOTAL) return;
    if (idx < O_WP1){
        int t = idx;
        int j = t & 7, lane = (t >> 3) & 63, gnt = (t >> 9) & 15, kk = t >> 13;
        int co = gnt*16 + (lane & 15), ci = (lane >> 4)*8 + j;
        pk[idx] = f2bf(W0[co*160 + ci*5 + kk]);
    } else if (idx < O_WP2){
        int t = idx - O_WP1;
        int j = t & 7, lane = (t >> 3) & 63, gnt = (t >> 9) & 15, kk = t >> 13;
        int kc = kk >> 3, s = kk & 7;
        int co = gnt*16 + (lane & 15), ci = s*32 + (lane >> 4)*8 + j;
        pk[idx] = f2bf(W1[co*1280 + ci*5 + kc]);
    } else if (idx < O_PROJ){
        int t = idx - O_WP2;
        int j = t & 7, lane = (t >> 3) & 63, gnt = (t >> 9) & 15, kk = t >> 13;
        int kc = kk >> 3, s = kk & 7;
        int co = gnt*16 + (lane & 15), ci = s*32 + (lane >> 4)*8 + j;
        pk[idx] = f2bf(W2[co*1280 + ci*5 + kc]);
    }
    else if (idx < O_VAL1) pk[idx] = pack_std_elem(proj_w, 256, idx - O_PROJ);
    else if (idx < O_POS1) pk[idx] = pack_std_elem(val_w1, 256, idx - O_VAL1);
    else if (idx < O_RES1) pk[idx] = pack_std_elem(pos_w1, 256, idx - O_POS1);
    else if (idx < O_VAL2) pk[idx] = pack_std_elem(res_w1, 256, idx - O_RES1);
    else if (idx < O_RES2) pk[idx] = pack_std_elem(val_w2, 128, idx - O_VAL2);
    else if (idx < O_POS2) pk[idx] = pack_std_elem(res_w2, 2048, idx - O_RES2);
    else if (idx < O_MIX)  pk[idx] = pack_pad_elem(pos_w2, 4, idx - O_POS2);
    else                   pk[idx] = pack_pad_elem(mix_w, 2, idx - O_MIX);
}

// ---------------- Kernel 1: MFMA conv, 2 batches per block, pipelined K-loop ----------------
#define HT_S 264
#define XT_S 32

__global__ __launch_bounds__(256, 2) void conv_mfma_kernel(
    const float* __restrict__ A,
    const float* __restrict__ B0, const float* __restrict__ B1, const float* __restrict__ B2,
    const unsigned short* __restrict__ wp0, const unsigned short* __restrict__ wp1,
    const unsigned short* __restrict__ wp2,
    unsigned short* __restrict__ pooled)
{
    __shared__ unsigned short xt[2][68 * XT_S];
    __shared__ unsigned short ht[2][68 * HT_S];

    const int tid  = threadIdx.x;
    const int b0   = blockIdx.x * 2;
    const int w    = tid >> 6;
    const int lane = tid & 63;
    const int l15  = lane & 15;
    const int q    = lane >> 4;
    const int w4   = w << 2;
    const int w64  = w << 6;
    const int q8   = q << 3;
    const int q4   = q << 2;
    const int lane8 = lane << 3;

    for (int i = tid; i < 4 * HT_S; i += 256){
        int r = i / HT_S, c = i - r * HT_S;
        int rr = (r < 2 ? r : r + 64);
        ht[0][rr * HT_S + c] = 0;
        ht[1][rr * HT_S + c] = 0;
    }
    if (tid < 128){
        int r = tid >> 5, c = tid & 31;
        int rr = (r < 2 ? r : r + 64);
        xt[0][rr * XT_S + c] = 0;
        xt[1][rr * XT_S + c] = 0;
    }
    #pragma unroll
    for (int bb = 0; bb < 2; ++bb){
        const float* Ab = A + (size_t)(b0 + bb) * 2048;
        int e0 = tid << 3;
        int t = e0 >> 5, c = e0 & 31;
        const float4* p = (const float4*)(Ab + e0);
        float4 v0 = p[0], v1 = p[1];
        union { unsigned short u[8]; bf16x8 v; } pkv;
        pkv.u[0]=f2bf(v0.x); pkv.u[1]=f2bf(v0.y); pkv.u[2]=f2bf(v0.z); pkv.u[3]=f2bf(v0.w);
        pkv.u[4]=f2bf(v1.x); pkv.u[5]=f2bf(v1.y); pkv.u[6]=f2bf(v1.z); pkv.u[7]=f2bf(v1.w);
        *(bf16x8*)&xt[bb][(t + 2) * XT_S + c] = pkv.v;
    }
    __syncthreads();

    f32x4 acc0[4][4], acc1[4][4];

#define ZERO2 \
    { _Pragma("unroll") for (int mt = 0; mt < 4; ++mt) \
      _Pragma("unroll") for (int nt = 0; nt < 4; ++nt){ \
          acc0[mt][nt] = (f32x4){0.f,0.f,0.f,0.f}; acc1[mt][nt] = (f32x4){0.f,0.f,0.f,0.f}; } }
#define LOADA_X(BUF, BB, KC) \
    { _Pragma("unroll") for (int mt = 0; mt < 4; ++mt) \
          BUF[mt] = *(const bf16x8*)&xt[BB][((mt << 4) + l15 + (KC)) * XT_S + q8]; }
#define LOADA_H(BUF, BB, KK) \
    { _Pragma("unroll") for (int mt = 0; mt < 4; ++mt) \
          BUF[mt] = *(const bf16x8*)&ht[BB][((mt << 4) + l15 + ((KK) >> 3)) * HT_S + (((KK) & 7) << 5) + q8]; }
#define LOADB_(BUF, KK, WP) \
    { _Pragma("unroll") for (int nt = 0; nt < 4; ++nt) \
          BUF[nt] = *(const bf16x8*)((WP) + ((((KK) << 4) + w4 + nt) << 9) + lane8); }
#define MF(ACC, AB, BB_) \
    { _Pragma("unroll") for (int mt = 0; mt < 4; ++mt) \
      _Pragma("unroll") for (int nt = 0; nt < 4; ++nt) \
          ACC[mt][nt] = __builtin_amdgcn_mfma_f32_16x16x32_bf16(AB[mt], BB_[nt], ACC[mt][nt], 0, 0, 0); }
#define EPI(ACC, BB, BIAS) \
    { float bv[4]; \
      _Pragma("unroll") for (int nt = 0; nt < 4; ++nt) bv[nt] = (BIAS)[w64 + (nt << 4) + l15]; \
      _Pragma("unroll") for (int mt = 0; mt < 4; ++mt) \
      _Pragma("unroll") for (int nt = 0; nt < 4; ++nt) \
      _Pragma("unroll") for (int r = 0; r < 4; ++r){ \
          float v = gelu_fast(ACC[mt][nt][r] + bv[nt]); \
          ht[BB][((mt << 4) + q4 + r + 2) * HT_S + w64 + (nt << 4) + l15] = f2bf(v); } }

// software-pipelined K-loop: every load issued >= 16 MFMAs (~270 cyc) before first use
#define CONV_LAYER2(WP) \
    { bf16x8 Bf0[4], Bf1[4], A0a[4], A1a[4], A0b[4], A1b[4]; \
      LOADB_(Bf0, 0, WP); \
      LOADA_H(A0a, 0, 0); LOADA_H(A1a, 1, 0); \
      for (int kk = 0; kk < 38; kk += 2){ \
          LOADB_(Bf1, kk + 1, WP); \
          LOADA_H(A0b, 0, kk + 1); \
          MF(acc0, A0a, Bf0); \
          LOADA_H(A1b, 1, kk + 1); \
          MF(acc1, A1a, Bf0); \
          LOADB_(Bf0, kk + 2, WP); \
          LOADA_H(A0a, 0, kk + 2); \
          MF(acc0, A0b, Bf1); \
          LOADA_H(A1a, 1, kk + 2); \
          MF(acc1, A1b, Bf1); \
      } \
      LOADB_(Bf1, 39, WP); \
      LOADA_H(A0b, 0, 39); \
      MF(acc0, A0a, Bf0); \
      LOADA_H(A1b, 1, 39); \
      MF(acc1, A1a, Bf0); \
      MF(acc0, A0b, Bf1); \
      MF(acc1, A1b, Bf1); }

    // ---- conv0 (small, 5 k-offsets) ----
    ZERO2;
    {
        bf16x8 Bf0[4], Bf1[4], Xa[4], Ya[4];
        LOADB_(Bf0, 0, wp0);
        LOADA_X(Xa, 0, 0); LOADA_X(Ya, 1, 0);
        #pragma unroll
        for (int kc = 0; kc < 5; ++kc){
            if (kc + 1 < 5) LOADB_(Bf1, kc + 1, wp0);
            MF(acc0, Xa, Bf0);
            MF(acc1, Ya, Bf0);
            if (kc + 1 < 5){
                LOADA_X(Xa, 0, kc + 1); LOADA_X(Ya, 1, kc + 1);
                #pragma unroll
                for (int nt = 0; nt < 4; ++nt) Bf0[nt] = Bf1[nt];
            }
        }
    }
    EPI(acc0, 0, B0);
    EPI(acc1, 1, B0);
    __syncthreads();

    // ---- conv1 ----
    ZERO2;
    CONV_LAYER2(wp1);
    __syncthreads();
    EPI(acc0, 0, B1);
    EPI(acc1, 1, B1);
    __syncthreads();

    // ---- conv2 + mean pool ----
    ZERO2;
    CONV_LAYER2(wp2);
    {
        float bv[4];
        #pragma unroll
        for (int nt = 0; nt < 4; ++nt) bv[nt] = B2[w64 + (nt << 4) + l15];
        #pragma unroll
        for (int bb = 0; bb < 2; ++bb){
            float s[4];
            #pragma unroll
            for (int nt = 0; nt < 4; ++nt){
                float acc_s = 0.f;
                #pragma unroll
                for (int mt = 0; mt < 4; ++mt)
                    #pragma unroll
                    for (int r = 0; r < 4; ++r){
                        float v = bb == 0 ? acc0[mt][nt][r] : acc1[mt][nt][r];
                        acc_s += gelu_fast(v + bv[nt]);
                    }
                s[nt] = acc_s;
            }
            #pragma unroll
            for (int nt = 0; nt < 4; ++nt){
                s[nt] += __shfl_xor(s[nt], 16);
                s[nt] += __shfl_xor(s[nt], 32);
            }
            if (q == 0){
                #pragma unroll
                for (int nt = 0; nt < 4; ++nt)
                    pooled[(size_t)(b0 + bb) * 256 + w64 + (nt << 4) + l15] = f2bf(s[nt] * (1.0f / 64.0f));
            }
        }
    }
}

// ---------------- Kernel 2a: heads stages A-C, 16 batches/block ----------------
#define AS 264

__global__ __launch_bounds__(256) void heads_a_kernel(
    const unsigned short* __restrict__ pooled,
    const float* __restrict__ proj_b, const float* __restrict__ val_b1,
    const float* __restrict__ pos_b1, const float* __restrict__ res_b1,
    const float* __restrict__ val_b2, const float* __restrict__ pos_b2,
    const float* __restrict__ mix_b,
    const unsigned short* __restrict__ pk,
    unsigned short* __restrict__ rh, float* __restrict__ meta,
    float* __restrict__ accums)
{
    __shared__ unsigned short pb [16 * AS];
    __shared__ unsigned short eb [16 * AS];
    __shared__ unsigned short vb [16 * AS];
    __shared__ unsigned short phb[16 * AS];
    __shared__ unsigned short rhb[16 * AS];
    __shared__ float av [16 * 132];
    __shared__ float avs[16 * 132];
    __shared__ float psort[16][4];
    __shared__ int   rank [16][4];
    __shared__ float qsh  [16][2];
    __shared__ float mlsh [16][2];
    __shared__ float sposh[16][4];

    const int tid  = threadIdx.x;
    const int b0   = blockIdx.x * 16;
    const int w    = tid >> 6;
    const int lane = tid & 63;
    const int l15  = lane & 15;
    const int q    = lane >> 4;
    const int q8   = q << 3;
    const int q4   = q << 2;

    {
        int g = tid >> 4, seg = tid & 15;
        const unsigned short* ps = pooled + ((size_t)(b0 + g) << 8) + (seg << 4);
        bf16x8 a0 = *(const bf16x8*)ps;
        bf16x8 a1 = *(const bf16x8*)(ps + 8);
        *(bf16x8*)&pb[g * AS + (seg << 4)]     = a0;
        *(bf16x8*)&pb[g * AS + (seg << 4) + 8] = a1;
    }
    __syncthreads();

#define HGEMM256(ASRC, GOFF, BIAS, DST) \
    { f32x4 hacc[4]; \
      _Pragma("unroll") for (int nt = 0; nt < 4; ++nt) hacc[nt] = (f32x4){0.f,0.f,0.f,0.f}; \
      _Pragma("unroll") for (int kk = 0; kk < 8; ++kk){ \
          bf16x8 af = *(const bf16x8*)&(ASRC)[l15 * AS + (kk << 5) + q8]; \
          _Pragma("unroll") for (int nt = 0; nt < 4; ++nt){ \
              bf16x8 bfr = *(const bf16x8*)(pk + (GOFF) + (size_t)((((kk << 4) + (w << 2) + nt) << 6) + lane) * 8); \
              hacc[nt] = __builtin_amdgcn_mfma_f32_16x16x32_bf16(af, bfr, hacc[nt], 0, 0, 0); } } \
      _Pragma("unroll") for (int nt = 0; nt < 4; ++nt){ \
          int n = (w << 6) + (nt << 4) + l15; \
          float bv = (BIAS)[n]; \
          _Pragma("unroll") for (int r = 0; r < 4; ++r) \
              (DST)[(q4 + r) * AS + n] = f2bf(gelu_fast(hacc[nt][r] + bv)); } }

    HGEMM256(pb, O_PROJ, proj_b, eb);
    __syncthreads();

    HGEMM256(eb, O_VAL1, val_b1, vb);
    HGEMM256(eb, O_POS1, pos_b1, phb);
    HGEMM256(eb, O_RES1, res_b1, rhb);
    __syncthreads();

    {
        f32x4 acc2[2];
        #pragma unroll
        for (int nt = 0; nt < 2; ++nt) acc2[nt] = (f32x4){0.f,0.f,0.f,0.f};
        #pragma unroll
        for (int kk = 0; kk < 8; ++kk){
            bf16x8 af = *(const bf16x8*)&vb[l15 * AS + (kk << 5) + q8];
            #pragma unroll
            for (int nt = 0; nt < 2; ++nt){
                bf16x8 bfr = *(const bf16x8*)(pk + O_VAL2 + (size_t)(((kk*8 + w*2 + nt) << 6) + lane) * 8);
                acc2[nt] = __builtin_amdgcn_mfma_f32_16x16x32_bf16(af, bfr, acc2[nt], 0, 0, 0);
            }
        }
        #pragma unroll
        for (int nt = 0; nt < 2; ++nt){
            int j = (w << 5) + (nt << 4) + l15;
            float bv = val_b2[j];
            #pragma unroll
            for (int r = 0; r < 4; ++r)
                av[(q4 + r) * 132 + j] = acc2[nt][r] + bv;
        }
    }
    if (w == 0){
        f32x4 accp = (f32x4){0.f,0.f,0.f,0.f};
        #pragma unroll
        for (int kk = 0; kk < 8; ++kk){
            bf16x8 af  = *(const bf16x8*)&phb[l15 * AS + (kk << 5) + q8];
            bf16x8 bfr = *(const bf16x8*)(pk + O_POS2 + (size_t)((kk << 6) + lane) * 8);
            accp = __builtin_amdgcn_mfma_f32_16x16x32_bf16(af, bfr, accp, 0, 0, 0);
        }
        if (l15 < 4){
            float bv = pos_b2[l15];
            #pragma unroll
            for (int r = 0; r < 4; ++r){
                float raw = accp[r] + bv;
                sposh[q4 + r][l15] = 63.0f / (1.0f + __expf(-raw));
            }
        }
    } else if (w == 1){
        f32x4 accm = (f32x4){0.f,0.f,0.f,0.f};
        #pragma unroll
        for (int kk = 0; kk < 8; ++kk){
            bf16x8 af  = *(const bf16x8*)&eb[l15 * AS + (kk << 5) + q8];
            bf16x8 bfr = *(const bf16x8*)(pk + O_MIX + (size_t)((kk << 6) + lane) * 8);
            accm = __builtin_amdgcn_mfma_f32_16x16x32_bf16(af, bfr, accm, 0, 0, 0);
        }
        if (l15 < 2){
            #pragma unroll
            for (int r = 0; r < 4; ++r)
                mlsh[q4 + r][l15] = accm[r] + mix_b[l15];
        }
    }
    __syncthreads();

    if (tid < 16){
        int g = tid;
        float sv[4] = { sposh[g][0], sposh[g][1], sposh[g][2], sposh[g][3] };
        #pragma unroll
        for (int i = 0; i < 4; ++i){
            int r = 0;
            #pragma unroll
            for (int jj = 0; jj < 4; ++jj){
                r += (sv[jj] < sv[i]) ? 1 : 0;
                if (jj < i) r += (sv[jj] == sv[i]) ? 1 : 0;
            }
            rank[g][i] = r;
            psort[g][r] = sv[i];
        }
        psort[g][0] = 0.0f; psort[g][3] = 63.0f;
        float p1 = psort[g][1], p2 = psort[g][2];
        float g1 = p1, g2 = p2 - p1, g3 = 63.0f - p2;
        const float MG = 10.5f;
        float r1 = fmaxf(MG - g1, 0.f), r2 = fmaxf(MG - g2, 0.f), r3 = fmaxf(MG - g3, 0.f);
        float sp = (r1*r1 + r2*r2 + r3*r3) * (1.0f / 3.0f);
        float l0 = mlsh[g][0], l1 = mlsh[g][1];
        float m = fmaxf(l0, l1);
        float e0 = __expf(l0 - m), e1 = __expf(l1 - m);
        float inv = 1.0f / (e0 + e1);
        float q0 = e0 * inv, q1 = e1 * inv;
        qsh[g][0] = q0; qsh[g][1] = q1;
        float entc = q0 * logf(q0 + 1e-8f) + q1 * logf(q1 + 1e-8f);
        atomicAdd(&accums[2], entc);
        atomicAdd(&accums[3], q0);
        atomicAdd(&accums[4], q1);
        atomicAdd(&accums[5], sp);
    }
    __syncthreads();

    #pragma unroll
    for (int u2 = 0; u2 < 8; ++u2){
        int idx2 = tid * 8 + u2;
        int g = idx2 >> 7, j = idx2 & 127;
        avs[g * 132 + rank[g][j >> 5] * 32 + (j & 31)] = av[g * 132 + j];
    }
    __syncthreads();

    {
        int g = tid >> 4, c16 = (tid & 15) << 4;
        bf16x8 a0 = *(const bf16x8*)&rhb[g * AS + c16];
        bf16x8 a1 = *(const bf16x8*)&rhb[g * AS + c16 + 8];
        unsigned short* dst = rh + ((size_t)(b0 + g) << 8) + c16;
        *(bf16x8*)dst       = a0;
        *(bf16x8*)(dst + 8) = a1;
    }
    if (tid < 132){
        for (int g = 0; g < 16; ++g){
            float v;
            if (tid < 128)       v = avs[g * 132 + tid];
            else if (tid == 128) v = psort[g][1];
            else if (tid == 129) v = psort[g][2];
            else if (tid == 130) v = qsh[g][0];
            else                 v = qsh[g][1];
            meta[(size_t)(b0 + g) * 132 + tid] = v;
        }
    }
}

// ---------------- Kernel 2b: residual GEMM + interp + recon/L1 losses ----------------
__global__ __launch_bounds__(256) void resid_loss_kernel(
    const float* __restrict__ A, const unsigned short* __restrict__ rh,
    const float* __restrict__ res_b2, const unsigned short* __restrict__ pk,
    const float* __restrict__ meta, float* __restrict__ accums)
{
    __shared__ float ml[16 * 132];
    __shared__ float wred[4], wred2[4];

    const int tid  = threadIdx.x;
    const int w    = tid >> 6;
    const int lane = tid & 63;
    const int l15  = lane & 15;
    const int q    = lane >> 4;
    const int q8   = q << 3;
    const int q4   = q << 2;
    const int bg   = blockIdx.x >> 2;
    const int cc   = blockIdx.x & 3;
    const int b0   = bg << 4;

    for (int i = tid; i < 16 * 132; i += 256)
        ml[i] = meta[(size_t)b0 * 132 + i];
    __syncthreads();

    f32x4 acc[8];
    #pragma unroll
    for (int nt = 0; nt < 8; ++nt) acc[nt] = (f32x4){0.f,0.f,0.f,0.f};
    #pragma unroll
    for (int kk = 0; kk < 8; ++kk){
        bf16x8 af = *(const bf16x8*)(rh + ((size_t)(b0 + l15) << 8) + (kk << 5) + q8);
        #pragma unroll
        for (int nt = 0; nt < 8; ++nt){
            int ntg = (cc << 5) + (w << 3) + nt;
            bf16x8 bfr = *(const bf16x8*)(pk + O_RES2 + (size_t)((kk << 7) + ntg) * 512 + (lane << 3));
            acc[nt] = __builtin_amdgcn_mfma_f32_16x16x32_bf16(af, bfr, acc[nt], 0, 0, 0);
        }
    }

    float lsq = 0.f, ll1 = 0.f;
    #pragma unroll
    for (int nt = 0; nt < 8; ++nt){
        int e = (cc << 9) + (w << 7) + (nt << 4) + l15;
        float rbv = res_b2[e];
        int t = e >> 5, d = e & 31;
        float tf = (float)t;
        #pragma unroll
        for (int r = 0; r < 4; ++r){
            int g = q4 + r;
            const float* mg = &ml[g * 132];
            float p1 = mg[128], p2 = mg[129], q0 = mg[130], q1 = mg[131];
            float res = acc[nt][r] + rbv;
            int cnt = (p1 <= tf) + (p2 <= tf) + (tf >= 63.0f);
            int idx = cnt < 2 ? cnt : 2;
            float left  = idx == 0 ? 0.0f : (idx == 1 ? p1 : p2);
            float right = idx == 0 ? p1   : (idx == 1 ? p2 : 63.0f);
            float wgt = (tf - left) / (right - left + 1e-8f);
            wgt = fminf(fmaxf(wgt, 0.f), 1.f);
            float vl = mg[idx * 32 + d];
            float vr = mg[idx * 32 + 32 + d];
            float coarse = vl + wgt * (vr - vl);
            float a = A[((size_t)(b0 + g) << 11) + e];
            float fine = coarse + res;
            float recon = q0 * coarse + q1 * fine;
            float dd = recon - a;
            lsq += dd * dd;
            ll1 += fabsf(res);
        }
    }
    #pragma unroll
    for (int off = 32; off > 0; off >>= 1){
        lsq += __shfl_down(lsq, off);
        ll1 += __shfl_down(ll1, off);
    }
    if (lane == 0){ wred[w] = lsq; wred2[w] = ll1; }
    __syncthreads();
    if (tid == 0){
        atomicAdd(&accums[0], wred[0] + wred[1] + wred[2] + wred[3]);
        atomicAdd(&accums[1], wred2[0] + wred2[1] + wred2[2] + wred2[3]);
    }
}

// ---------------- Kernel 3: finalize ----------------
__global__ void finalize_kernel(const float* __restrict__ accums, float* __restrict__ out){
    float rs = accums[0], l1s = accums[1], ents = accums[2];
    float q0s = accums[3], q1s = accums[4], sps = accums[5];
    const float invN = 1.0f / (4096.0f * 2048.0f);
    const float invB = 1.0f / 4096.0f;
    float recon_loss = rs * invN;
    float l1   = l1s * invN;
    float ent  = -ents * invB;
    float mq0  = q0s * invB - 0.5f, mq1 = q1s * invB - 0.5f;
    float balance = mq0*mq0 + mq1*mq1;
    float spacing = sps * invB;
    out[0] = recon_loss + 0.05f*l1 + 0.01f*ent + 0.1f*balance + 0.1f*spacing;
}

extern "C" void kernel_launch(void* const* d_in, const int* in_sizes, int n_in,
                              void* d_out, int out_size, void* d_ws, size_t ws_size,
                              hipStream_t stream)
{
    const float* A      = (const float*)d_in[0];
    const float* W0     = (const float*)d_in[1];
    const float* B0     = (const float*)d_in[2];
    const float* W1     = (const float*)d_in[3];
    const float* B1     = (const float*)d_in[4];
    const float* W2     = (const float*)d_in[5];
    const float* B2     = (const float*)d_in[6];
    const float* proj_w = (const float*)d_in[7];
    const float* proj_b = (const float*)d_in[8];
    const float* val_w1 = (const float*)d_in[9];
    const float* val_b1 = (const float*)d_in[10];
    const float* val_w2 = (const float*)d_in[11];
    const float* val_b2 = (const float*)d_in[12];
    const float* pos_w1 = (const float*)d_in[13];
    const float* pos_b1 = (const float*)d_in[14];
    const float* pos_w2 = (const float*)d_in[15];
    const float* pos_b2 = (const float*)d_in[16];
    const float* res_w1 = (const float*)d_in[17];
    const float* res_b1 = (const float*)d_in[18];
    const float* res_w2 = (const float*)d_in[19];
    const float* res_b2 = (const float*)d_in[20];
    const float* mix_w  = (const float*)d_in[21];
    const float* mix_b  = (const float*)d_in[22];

    char* wsb = (char*)d_ws;
    float* accums = (float*)wsb;
    unsigned short* pooled = (unsigned short*)(wsb + 256);
    unsigned short* pkbuf  = (unsigned short*)(wsb + 256 + 2097152);
    unsigned short* rhbuf  = (unsigned short*)(wsb + 256 + 2097152 + (size_t)PK_TOTAL * 2);
    float* metabuf = (float*)(wsb + 256 + 2097152 + (size_t)PK_TOTAL * 2 + 2097152);

    hipMemsetAsync(accums, 0, 64 * sizeof(float), stream);

    hipLaunchKernelGGL(pack_weights, dim3((PK_TOTAL + 255) / 256), dim3(256), 0, stream,
                       W0, W1, W2, proj_w, val_w1, pos_w1, res_w1,
                       val_w2, res_w2, pos_w2, mix_w, pkbuf);

    hipLaunchKernelGGL(conv_mfma_kernel, dim3(NB / 2), dim3(256), 0, stream,
                       A, B0, B1, B2,
                       pkbuf + O_WP0, pkbuf + O_WP1, pkbuf + O_WP2, pooled);

    hipLaunchKernelGGL(heads_a_kernel, dim3(NB / 16), dim3(256), 0, stream,
                       pooled, proj_b, val_b1, pos_b1, res_b1, val_b2, pos_b2, mix_b,
                       pkbuf, rhbuf, metabuf, accums);

    hipLaunchKernelGGL(resid_loss_kernel, dim3(NB / 16 * 4), dim3(256), 0, stream,
                       A, rhbuf, res_b2, pkbuf, metabuf, accums);

    hipLaunchKernelGGL(finalize_kernel, dim3(1), dim3(1), 0, stream,
                       accums, (float*)d_out);
}